// Round 1
// baseline (553.056 us; speedup 1.0000x reference)
//
#include <hip/hip_runtime.h>
#include <hip/hip_bf16.h>

// Problem constants
#define B_   8
#define S_   1024
#define D_   128
#define NH_  8
#define HD_  16
#define E_   4
#define HFF_ 512
#define NTOK (B_*S_)

// ---------------------------------------------------------------------------
// Generic 64x64-tile fp32 GEMM: C[M,N] = A[M,K] @ Bm[K,N] (+bias, mode extras)
// MODE 0: C = A@B + bias
// MODE 1: C = A@B + bias + extra (residual)
// MODE 2: C = relu(A@B + bias)
// MODE 3: C += gates[row*E + ge] * (A@B + bias)
// Requires M%64==0, N%64==0, K%128==0 (all true here).
// ---------------------------------------------------------------------------
template<int MODE>
__global__ __launch_bounds__(256)
void gemm64(const float* __restrict__ A, const float* __restrict__ Bm,
            const float* __restrict__ bias, const float* __restrict__ extra,
            const float* __restrict__ gates, int ge,
            float* __restrict__ C, int M, int N, int K)
{
    __shared__ float As[128][64];   // [k][m] (transposed A tile)
    __shared__ float Bs[128][64];   // [k][n]
    const int bm = blockIdx.x * 64;
    const int bn = blockIdx.y * 64;
    const int tid = threadIdx.x;
    const int tx = tid & 15, ty = tid >> 4;   // 16x16 threads, 4x4 outputs each

    float acc[4][4] = {};

    for (int k0 = 0; k0 < K; k0 += 128) {
        #pragma unroll
        for (int i = 0; i < 8; i++) {
            int idx = tid + i * 256;          // 0..2047
            // A tile: 64 rows x 32 float4 (along k)
            int m  = idx >> 5;
            int kq = idx & 31;
            float4 v = *(const float4*)&A[(size_t)(bm + m) * K + k0 + kq * 4];
            As[kq*4+0][m] = v.x; As[kq*4+1][m] = v.y;
            As[kq*4+2][m] = v.z; As[kq*4+3][m] = v.w;
            // B tile: 128 rows x 16 float4 (along n)
            int kk = idx >> 4;
            int nq = idx & 15;
            *(float4*)&Bs[kk][nq*4] = *(const float4*)&Bm[(size_t)(k0 + kk) * N + bn + nq * 4];
        }
        __syncthreads();
        #pragma unroll 4
        for (int k = 0; k < 128; k++) {
            float4 av = *(const float4*)&As[k][ty*4];
            float4 bv = *(const float4*)&Bs[k][tx*4];
            acc[0][0] += av.x*bv.x; acc[0][1] += av.x*bv.y; acc[0][2] += av.x*bv.z; acc[0][3] += av.x*bv.w;
            acc[1][0] += av.y*bv.x; acc[1][1] += av.y*bv.y; acc[1][2] += av.y*bv.z; acc[1][3] += av.y*bv.w;
            acc[2][0] += av.z*bv.x; acc[2][1] += av.z*bv.y; acc[2][2] += av.z*bv.z; acc[2][3] += av.z*bv.w;
            acc[3][0] += av.w*bv.x; acc[3][1] += av.w*bv.y; acc[3][2] += av.w*bv.z; acc[3][3] += av.w*bv.w;
        }
        __syncthreads();
    }

    const int row0 = bm + ty*4, col0 = bn + tx*4;
    float4 bv = *(const float4*)&bias[col0];
    #pragma unroll
    for (int i = 0; i < 4; i++) {
        size_t off = (size_t)(row0 + i) * N + col0;
        float4 r = make_float4(acc[i][0]+bv.x, acc[i][1]+bv.y, acc[i][2]+bv.z, acc[i][3]+bv.w);
        if (MODE == 1) {
            float4 e4 = *(const float4*)&extra[off];
            r.x += e4.x; r.y += e4.y; r.z += e4.z; r.w += e4.w;
        }
        if (MODE == 2) {
            r.x = fmaxf(r.x, 0.f); r.y = fmaxf(r.y, 0.f);
            r.z = fmaxf(r.z, 0.f); r.w = fmaxf(r.w, 0.f);
        }
        if (MODE == 3) {
            float g = gates[(size_t)(row0 + i) * E_ + ge];
            float4 old = *(const float4*)&C[off];
            r.x = old.x + g*r.x; r.y = old.y + g*r.y;
            r.z = old.z + g*r.z; r.w = old.w + g*r.w;
        }
        *(float4*)&C[off] = r;
    }
}

// ---------------------------------------------------------------------------
// Attention: per (b,h), softmax(q k^T / 4) v.  K/V staged in LDS in 512-row
// chunks (64KB static LDS), one q-row per thread, online softmax.
// grid (B*NH, S/256), block 256.
// ---------------------------------------------------------------------------
__global__ __launch_bounds__(256)
void attn_fused(const float* __restrict__ qkv, float* __restrict__ o)
{
    __shared__ float Ks[512][16];
    __shared__ float Vs[512][16];
    const int bh = blockIdx.x;
    const int b = bh >> 3, h = bh & 7;
    const float* base = qkv + (size_t)b * S_ * (3*D_);
    const int s = blockIdx.y * 256 + threadIdx.x;

    float q[16];
    {
        const float* qp = base + (size_t)s * (3*D_) + h * HD_;
        #pragma unroll
        for (int d = 0; d < 16; d++) q[d] = qp[d] * 0.25f;   // 1/sqrt(16)
    }

    float m = -1e30f, l = 0.f, oa[16] = {};

    for (int c = 0; c < 2; c++) {
        __syncthreads();
        for (int idx = threadIdx.x; idx < 512*4; idx += 256) {
            int j = idx >> 2, dq = idx & 3;
            const float* kp = base + (size_t)(c*512 + j) * (3*D_) + D_ + h*HD_ + dq*4;
            *(float4*)&Ks[j][dq*4] = *(const float4*)kp;
            *(float4*)&Vs[j][dq*4] = *(const float4*)(kp + D_);
        }
        __syncthreads();

        for (int j = 0; j < 512; j++) {
            float4 k0 = *(const float4*)&Ks[j][0];
            float4 k1 = *(const float4*)&Ks[j][4];
            float4 k2 = *(const float4*)&Ks[j][8];
            float4 k3 = *(const float4*)&Ks[j][12];
            float sc = q[0]*k0.x + q[1]*k0.y + q[2]*k0.z + q[3]*k0.w
                     + q[4]*k1.x + q[5]*k1.y + q[6]*k1.z + q[7]*k1.w
                     + q[8]*k2.x + q[9]*k2.y + q[10]*k2.z + q[11]*k2.w
                     + q[12]*k3.x + q[13]*k3.y + q[14]*k3.z + q[15]*k3.w;
            if (sc > m) {   // rare after warm-up
                float r = __expf(m - sc);
                l *= r;
                #pragma unroll
                for (int d = 0; d < 16; d++) oa[d] *= r;
                m = sc;
            }
            float p = __expf(sc - m);
            l += p;
            float4 v0 = *(const float4*)&Vs[j][0];
            float4 v1 = *(const float4*)&Vs[j][4];
            float4 v2 = *(const float4*)&Vs[j][8];
            float4 v3 = *(const float4*)&Vs[j][12];
            oa[0] += p*v0.x; oa[1] += p*v0.y; oa[2]  += p*v0.z; oa[3]  += p*v0.w;
            oa[4] += p*v1.x; oa[5] += p*v1.y; oa[6]  += p*v1.z; oa[7]  += p*v1.w;
            oa[8] += p*v2.x; oa[9] += p*v2.y; oa[10] += p*v2.z; oa[11] += p*v2.w;
            oa[12]+= p*v3.x; oa[13]+= p*v3.y; oa[14] += p*v3.z; oa[15] += p*v3.w;
        }
    }

    float inv = 1.f / l;
    float* op = o + ((size_t)b * S_ + s) * D_ + h * HD_;
    #pragma unroll
    for (int d4 = 0; d4 < 4; d4++) {
        float4 r = make_float4(oa[d4*4+0]*inv, oa[d4*4+1]*inv, oa[d4*4+2]*inv, oa[d4*4+3]*inv);
        *(float4*)&op[d4*4] = r;
    }
}

// ---------------------------------------------------------------------------
// InstanceNorm over sequence axis: stats per (b, d) channel.
// Phase 1: grid (B, 8 chunks), 128 threads (one per channel d).
// input v = a[...] (+ b2p[...] if non-null)
// ---------------------------------------------------------------------------
__global__ __launch_bounds__(128)
void in_stats_partial(const float* __restrict__ a, const float* __restrict__ b2p,
                      float* __restrict__ part)
{
    const int bb = blockIdx.x, chunk = blockIdx.y, d = threadIdx.x;
    const size_t base = (size_t)bb * S_ * D_ + (size_t)chunk * (S_/8) * D_ + d;
    float sum = 0.f, sq = 0.f;
    for (int s = 0; s < S_/8; s++) {
        float v = a[base + (size_t)s * D_];
        if (b2p) v += b2p[base + (size_t)s * D_];
        sum += v; sq += v * v;
    }
    ((float2*)part)[(bb*8 + chunk)*D_ + d] = make_float2(sum, sq);
}

__global__ __launch_bounds__(256)
void in_stats_combine(const float* __restrict__ part, float* __restrict__ stats)
{
    int bd = blockIdx.x * 256 + threadIdx.x;
    if (bd >= B_ * D_) return;
    int bb = bd / D_, d = bd % D_;
    float sum = 0.f, sq = 0.f;
    const float2* pp = (const float2*)part;
    for (int c = 0; c < 8; c++) {
        float2 v = pp[(bb*8 + c)*D_ + d];
        sum += v.x; sq += v.y;
    }
    const float invS = 1.f / (float)S_;
    float mu  = sum * invS;
    float var = sq * invS - mu * mu;   // biased, matches torch InstanceNorm
    ((float2*)stats)[bd] = make_float2(mu, rsqrtf(var + 1e-5f));
}

// Apply: out = ((a (+b2p)) - mu) * rstd * w + bias ; vectorized over float4.
__global__ __launch_bounds__(256)
void in_apply(const float* __restrict__ a, const float* __restrict__ b2p,
              const float* __restrict__ stats, const float* __restrict__ w,
              const float* __restrict__ bias, float* __restrict__ outp)
{
    size_t i4 = (size_t)blockIdx.x * 256 + threadIdx.x;   // over B*S*D/4
    int dq = (int)(i4 & 31);               // D/4 = 32
    int bidx = (int)((i4 >> 5) / S_);      // batch
    float4 v = ((const float4*)a)[i4];
    if (b2p) {
        float4 u = ((const float4*)b2p)[i4];
        v.x += u.x; v.y += u.y; v.z += u.z; v.w += u.w;
    }
    const float2* st = (const float2*)stats;
    int d0 = dq * 4;
    float2 s0 = st[bidx*D_ + d0 + 0];
    float2 s1 = st[bidx*D_ + d0 + 1];
    float2 s2 = st[bidx*D_ + d0 + 2];
    float2 s3 = st[bidx*D_ + d0 + 3];
    float4 r;
    r.x = (v.x - s0.x) * s0.y * w[d0+0] + bias[d0+0];
    r.y = (v.y - s1.x) * s1.y * w[d0+1] + bias[d0+1];
    r.z = (v.z - s2.x) * s2.y * w[d0+2] + bias[d0+2];
    r.w = (v.w - s3.x) * s3.y * w[d0+3] + bias[d0+3];
    ((float4*)outp)[i4] = r;
}

// ---------------------------------------------------------------------------
// Gating: logits = h @ w_gate [D,E]; top-2 (stable ties) + softmax -> gates[N,E]
// One token per thread.
// ---------------------------------------------------------------------------
__global__ __launch_bounds__(256)
void gate_kernel(const float* __restrict__ h, const float* __restrict__ wg,
                 float* __restrict__ gates)
{
    __shared__ float wgs[D_ * E_];
    for (int i = threadIdx.x; i < D_ * E_; i += 256) wgs[i] = wg[i];
    __syncthreads();
    int t = blockIdx.x * 256 + threadIdx.x;
    const float4* hp = (const float4*)(h + (size_t)t * D_);
    float a0 = 0.f, a1 = 0.f, a2 = 0.f, a3 = 0.f;
    #pragma unroll 8
    for (int dq = 0; dq < 32; dq++) {
        float4 xv = hp[dq];
        const float* w0 = &wgs[dq * 16];
        a0 += xv.x*w0[0] + xv.y*w0[4] + xv.z*w0[8]  + xv.w*w0[12];
        a1 += xv.x*w0[1] + xv.y*w0[5] + xv.z*w0[9]  + xv.w*w0[13];
        a2 += xv.x*w0[2] + xv.y*w0[6] + xv.z*w0[10] + xv.w*w0[14];
        a3 += xv.x*w0[3] + xv.y*w0[7] + xv.z*w0[11] + xv.w*w0[15];
    }
    float lv[4] = {a0, a1, a2, a3};
    int i0 = 0; float m0 = lv[0];
    #pragma unroll
    for (int k = 1; k < 4; k++) if (lv[k] > m0) { m0 = lv[k]; i0 = k; }
    int i1 = -1; float m1 = -1e30f;
    #pragma unroll
    for (int k = 0; k < 4; k++) {
        if (k == i0) continue;
        if (lv[k] > m1) { m1 = lv[k]; i1 = k; }
    }
    float te = __expf(m1 - m0);        // <= 1
    float g0 = 1.f / (1.f + te);
    float g1 = te * g0;
    float g[4] = {0.f, 0.f, 0.f, 0.f};
    g[i0] = g0; g[i1] = g1;
    *(float4*)&gates[(size_t)t * E_] = make_float4(g[0], g[1], g[2], g[3]);
}

// ---------------------------------------------------------------------------
// Launch
// ---------------------------------------------------------------------------
extern "C" void kernel_launch(void* const* d_in, const int* in_sizes, int n_in,
                              void* d_out, int out_size, void* d_ws, size_t ws_size,
                              hipStream_t stream)
{
    const float* x    = (const float*)d_in[0];
    const float* Wqkv = (const float*)d_in[1];
    const float* bqkv = (const float*)d_in[2];
    const float* Wo   = (const float*)d_in[3];
    const float* bo   = (const float*)d_in[4];
    const float* n1w  = (const float*)d_in[5];
    const float* n1b  = (const float*)d_in[6];
    const float* n2w  = (const float*)d_in[7];
    const float* n2b  = (const float*)d_in[8];
    const float* wg   = (const float*)d_in[9];
    const float* W1   = (const float*)d_in[10];
    const float* b1   = (const float*)d_in[11];
    const float* W2   = (const float*)d_in[12];
    const float* b2   = (const float*)d_in[13];

    // Workspace layout (max ~28.6 MB):
    //  [0,12M)   qkv  (later reused as hid [0,16M))
    //  [12,16M)  attn_o
    //  [16,20M)  t (proj+residual)
    //  [20,24M)  h (norm1 out, MoE input + residual)
    //  [24,28M)  y (MoE out)
    //  [28M..)   gates (128KB), partial stats (64KB), stats (8KB)
    char* ws = (char*)d_ws;
    float* qkv   = (float*)(ws);
    float* hid   = (float*)(ws);                       // reuse after attention
    float* attno = (float*)(ws + 12u*1024*1024);
    float* t     = (float*)(ws + 16u*1024*1024);
    float* h     = (float*)(ws + 20u*1024*1024);
    float* y     = (float*)(ws + 24u*1024*1024);
    float* gates = (float*)(ws + 28u*1024*1024);
    float* part  = (float*)(ws + 28u*1024*1024 + 256u*1024);
    float* stats = (float*)(ws + 28u*1024*1024 + 512u*1024);

    dim3 blk(256);

    // 1. QKV projection: [8192,128]@[128,384]+b
    gemm64<0><<<dim3(128, 6), blk, 0, stream>>>(x, Wqkv, bqkv, nullptr, nullptr, 0,
                                                qkv, NTOK, 3*D_, D_);
    // 2. attention
    attn_fused<<<dim3(B_*NH_, 4), blk, 0, stream>>>(qkv, attno);
    // 3. out-proj + bias + residual(x)
    gemm64<1><<<dim3(128, 2), blk, 0, stream>>>(attno, Wo, bo, x, nullptr, 0,
                                                t, NTOK, D_, D_);
    // 4. InstanceNorm 1
    in_stats_partial<<<dim3(B_, 8), dim3(128), 0, stream>>>(t, nullptr, part);
    in_stats_combine<<<dim3(4), blk, 0, stream>>>(part, stats);
    in_apply<<<dim3(1024), blk, 0, stream>>>(t, nullptr, stats, n1w, n1b, h);
    // 5. gating
    gate_kernel<<<dim3(NTOK/256), blk, 0, stream>>>(h, wg, gates);
    // 6. MoE FFN (dense over experts; gates zero the non-selected)
    hipMemsetAsync(y, 0, (size_t)NTOK * D_ * sizeof(float), stream);
    for (int e = 0; e < E_; e++) {
        gemm64<2><<<dim3(128, 8), blk, 0, stream>>>(h, W1 + (size_t)e*D_*HFF_,
                                                    b1 + e*HFF_, nullptr, nullptr, 0,
                                                    hid, NTOK, HFF_, D_);
        gemm64<3><<<dim3(128, 2), blk, 0, stream>>>(hid, W2 + (size_t)e*HFF_*D_,
                                                    b2 + e*D_, nullptr, gates, e,
                                                    y, NTOK, D_, HFF_);
    }
    // 7. InstanceNorm 2 over (y + h) -> d_out
    in_stats_partial<<<dim3(B_, 8), dim3(128), 0, stream>>>(y, h, part);
    in_stats_combine<<<dim3(4), blk, 0, stream>>>(part, stats);
    in_apply<<<dim3(1024), blk, 0, stream>>>(y, h, stats, n2w, n2b, (float*)d_out);
}

// Round 2
// 321.283 us; speedup vs baseline: 1.7214x; 1.7214x over previous
//
#include <hip/hip_runtime.h>
#include <hip/hip_bf16.h>

#define B_   8
#define S_   1024
#define D_   128
#define NH_  8
#define HD_  16
#define E_   4
#define HFF_ 512
#define NTOK (B_*S_)

typedef unsigned short ushort_t;
typedef __attribute__((ext_vector_type(8))) short bf16x8;
typedef __attribute__((ext_vector_type(4))) float f32x4;

static __device__ __forceinline__ ushort_t f2bf(float f) {
    union { float f; unsigned u; } v; v.f = f;
    unsigned r = v.u + 0x7FFF + ((v.u >> 16) & 1);   // RNE
    return (ushort_t)(r >> 16);
}

// ---------------------------------------------------------------------------
// prep: convert x to bf16 (linear) and all weights to bf16 TRANSPOSED [N][K]
// grid (1024, 5)
// ---------------------------------------------------------------------------
__global__ __launch_bounds__(256)
void prep(const float* __restrict__ x, const float* __restrict__ Wqkv,
          const float* __restrict__ Wo, const float* __restrict__ W1,
          const float* __restrict__ W2,
          ushort_t* __restrict__ xb, ushort_t* __restrict__ Wqkv_t,
          ushort_t* __restrict__ Wo_t, ushort_t* __restrict__ W1t,
          ushort_t* __restrict__ W2t)
{
    const int seg = blockIdx.y;
    const int i = blockIdx.x * 256 + threadIdx.x;
    if (seg == 0) {                       // x: 1048576 elems, 4/thread
        float4 v = ((const float4*)x)[i];
        ushort4 u; u.x = f2bf(v.x); u.y = f2bf(v.y); u.z = f2bf(v.z); u.w = f2bf(v.w);
        ((ushort4*)xb)[i] = u;
    } else if (seg == 1) {                // Wqkv [128][384] -> [384][128]
        if (i < D_ * 3 * D_) {
            int r = i / (3 * D_), c = i % (3 * D_);
            Wqkv_t[c * D_ + r] = f2bf(Wqkv[i]);
        }
    } else if (seg == 2) {                // Wo [128][128] -> T
        if (i < D_ * D_) {
            int r = i >> 7, c = i & 127;
            Wo_t[c * D_ + r] = f2bf(Wo[i]);
        }
    } else if (seg == 3) {                // W1 [4][128][512] -> [4][512][128]
        int e = i >> 16, rem = i & 65535, r = rem >> 9, c = rem & 511;
        W1t[e * 65536 + c * 128 + r] = f2bf(W1[i]);
    } else {                              // W2 [4][512][128] -> [4][128][512]
        int e = i >> 16, rem = i & 65535, r = rem >> 7, c = rem & 127;
        W2t[e * 65536 + c * 512 + r] = f2bf(W2[i]);
    }
}

// ---------------------------------------------------------------------------
// MFMA bf16 GEMM: C[M,N] = A[M,K] @ Bt[N,K]^T + bias, 64x64 tile, 1 wave.
// MODE 0: C = .. + bias            (f32 or bf16 out per OUTBF)
// MODE 1: C = .. + bias + extra    (f32 residual)
// MODE 2: C = relu(.. + bias)
// MODE 3: C += gates[row*E+ge] * (.. + bias)   (f32, pre-zeroed)
// ---------------------------------------------------------------------------
template<int MODE, int OUTBF>
__global__ __launch_bounds__(64)
void gemm_mfma(const ushort_t* __restrict__ A, const ushort_t* __restrict__ Bt,
               const float* __restrict__ bias, const float* __restrict__ extra,
               const float* __restrict__ gates, int ge,
               void* __restrict__ Cout, int M, int N, int K)
{
    __shared__ __align__(16) ushort_t As[4][64][8];   // [k-chunk][m][8k]
    __shared__ __align__(16) ushort_t Bs[4][64][8];   // [k-chunk][n][8k]
    const int bm = blockIdx.x * 64;
    const int bn = blockIdx.y * 64;
    const int l = threadIdx.x;
    const int lc = l & 15, lg = l >> 4;

    f32x4 acc[4][4] = {};

    const ushort_t* ap = A + (size_t)(bm + l) * K;
    const ushort_t* bp = Bt + (size_t)(bn + l) * K;

    for (int k0 = 0; k0 < K; k0 += 32) {
        #pragma unroll
        for (int c = 0; c < 4; c++) {
            *(bf16x8*)As[c][l] = *(const bf16x8*)(ap + k0 + c * 8);
            *(bf16x8*)Bs[c][l] = *(const bf16x8*)(bp + k0 + c * 8);
        }
        __syncthreads();
        bf16x8 af[4], bfr[4];
        #pragma unroll
        for (int f = 0; f < 4; f++) {
            af[f]  = *(const bf16x8*)As[lg][f * 16 + lc];
            bfr[f] = *(const bf16x8*)Bs[lg][f * 16 + lc];
        }
        #pragma unroll
        for (int fm = 0; fm < 4; fm++)
            #pragma unroll
            for (int fn = 0; fn < 4; fn++)
                acc[fm][fn] = __builtin_amdgcn_mfma_f32_16x16x32_bf16(
                    af[fm], bfr[fn], acc[fm][fn], 0, 0, 0);
        __syncthreads();
    }

    // C/D layout (verified): col = lane&15, row = (lane>>4)*4 + reg
    #pragma unroll
    for (int fm = 0; fm < 4; fm++) {
        #pragma unroll
        for (int r = 0; r < 4; r++) {
            const int row = bm + fm * 16 + lg * 4 + r;
            float g = 0.f;
            if (MODE == 3) g = gates[(size_t)row * E_ + ge];
            #pragma unroll
            for (int fn = 0; fn < 4; fn++) {
                const int col = bn + fn * 16 + lc;
                float v = acc[fm][fn][r] + bias[col];
                const size_t off = (size_t)row * N + col;
                if (MODE == 1) v += extra[off];
                if (MODE == 2) v = fmaxf(v, 0.f);
                if (MODE == 3) {
                    ((float*)Cout)[off] += g * v;
                } else if (OUTBF) {
                    ((ushort_t*)Cout)[off] = f2bf(v);
                } else {
                    ((float*)Cout)[off] = v;
                }
            }
        }
    }
}

// ---------------------------------------------------------------------------
// Attention partials: grid (B*NH, S/256, 2 j-chunks), block 256.
// Each block: 256 q rows vs 512 keys; online softmax; writes (m,l,oa[16])
// padded to 20 floats.
// ---------------------------------------------------------------------------
__global__ __launch_bounds__(256)
void attn_part(const float* __restrict__ qkv, float* __restrict__ part)
{
    __shared__ float Ks[512][16];
    __shared__ float Vs[512][16];
    const int bh = blockIdx.x;
    const int b = bh >> 3, h = bh & 7;
    const int jc = blockIdx.z;
    const float* base = qkv + (size_t)b * S_ * (3 * D_);
    const int s = blockIdx.y * 256 + threadIdx.x;

    float q[16];
    {
        const float* qp = base + (size_t)s * (3 * D_) + h * HD_;
        #pragma unroll
        for (int d = 0; d < 16; d++) q[d] = qp[d] * 0.25f;   // 1/sqrt(16)
    }

    for (int idx = threadIdx.x; idx < 512 * 4; idx += 256) {
        int j = idx >> 2, dq = idx & 3;
        const float* kp = base + (size_t)(jc * 512 + j) * (3 * D_) + D_ + h * HD_ + dq * 4;
        *(float4*)&Ks[j][dq * 4] = *(const float4*)kp;
        *(float4*)&Vs[j][dq * 4] = *(const float4*)(kp + D_);
    }
    __syncthreads();

    float m = -1e30f, l = 0.f, oa[16] = {};

    for (int j0 = 0; j0 < 512; j0 += 8) {
        float sc[8];
        #pragma unroll
        for (int i = 0; i < 8; i++) {
            const float* kr = Ks[j0 + i];
            float4 k0 = *(const float4*)&kr[0];
            float4 k1 = *(const float4*)&kr[4];
            float4 k2 = *(const float4*)&kr[8];
            float4 k3 = *(const float4*)&kr[12];
            sc[i] = q[0]*k0.x + q[1]*k0.y + q[2]*k0.z + q[3]*k0.w
                  + q[4]*k1.x + q[5]*k1.y + q[6]*k1.z + q[7]*k1.w
                  + q[8]*k2.x + q[9]*k2.y + q[10]*k2.z + q[11]*k2.w
                  + q[12]*k3.x + q[13]*k3.y + q[14]*k3.z + q[15]*k3.w;
        }
        float tm = sc[0];
        #pragma unroll
        for (int i = 1; i < 8; i++) tm = fmaxf(tm, sc[i]);
        if (tm > m) {
            float r = __expf(m - tm);
            l *= r;
            #pragma unroll
            for (int d = 0; d < 16; d++) oa[d] *= r;
            m = tm;
        }
        #pragma unroll
        for (int i = 0; i < 8; i++) {
            float p = __expf(sc[i] - m);
            l += p;
            const float* vr = Vs[j0 + i];
            float4 v0 = *(const float4*)&vr[0];
            float4 v1 = *(const float4*)&vr[4];
            float4 v2 = *(const float4*)&vr[8];
            float4 v3 = *(const float4*)&vr[12];
            oa[0] += p*v0.x; oa[1] += p*v0.y; oa[2]  += p*v0.z; oa[3]  += p*v0.w;
            oa[4] += p*v1.x; oa[5] += p*v1.y; oa[6]  += p*v1.z; oa[7]  += p*v1.w;
            oa[8] += p*v2.x; oa[9] += p*v2.y; oa[10] += p*v2.z; oa[11] += p*v2.w;
            oa[12]+= p*v3.x; oa[13]+= p*v3.y; oa[14] += p*v3.z; oa[15] += p*v3.w;
        }
    }

    float* pp = part + (((size_t)(bh * 2 + jc) * 1024) + s) * 20;
    *(float4*)&pp[0]  = make_float4(m, l, oa[0], oa[1]);
    *(float4*)&pp[4]  = make_float4(oa[2], oa[3], oa[4], oa[5]);
    *(float4*)&pp[8]  = make_float4(oa[6], oa[7], oa[8], oa[9]);
    *(float4*)&pp[12] = make_float4(oa[10], oa[11], oa[12], oa[13]);
    *(float4*)&pp[16] = make_float4(oa[14], oa[15], 0.f, 0.f);
}

// Merge 2 partials per (bh, q); write attention output as bf16 [B*S][D].
__global__ __launch_bounds__(256)
void attn_combine(const float* __restrict__ part, ushort_t* __restrict__ o)
{
    const int t = blockIdx.x * 256 + threadIdx.x;   // 65536
    const int bh = t >> 10, q = t & 1023;
    const int b = bh >> 3, h = bh & 7;
    const float* p0 = part + (((size_t)(bh * 2 + 0) * 1024) + q) * 20;
    const float* p1 = part + (((size_t)(bh * 2 + 1) * 1024) + q) * 20;
    float m0 = p0[0], l0 = p0[1], m1 = p1[0], l1 = p1[1];
    float M = fmaxf(m0, m1);
    float e0 = __expf(m0 - M), e1 = __expf(m1 - M);
    float inv = 1.f / (l0 * e0 + l1 * e1);
    ushort_t* op = o + ((size_t)(b * S_ + q)) * D_ + h * HD_;
    #pragma unroll
    for (int d = 0; d < 16; d++) {
        op[d] = f2bf((p0[2 + d] * e0 + p1[2 + d] * e1) * inv);
    }
}

// ---------------------------------------------------------------------------
// InstanceNorm over sequence axis (per (b,d) channel)
// ---------------------------------------------------------------------------
__global__ __launch_bounds__(128)
void in_stats_partial(const float* __restrict__ a, const float* __restrict__ b2p,
                      float* __restrict__ part)
{
    const int bb = blockIdx.x, chunk = blockIdx.y, d = threadIdx.x;
    const size_t base = (size_t)bb * S_ * D_ + (size_t)chunk * (S_ / 8) * D_ + d;
    float sum = 0.f, sq = 0.f;
    for (int s = 0; s < S_ / 8; s++) {
        float v = a[base + (size_t)s * D_];
        if (b2p) v += b2p[base + (size_t)s * D_];
        sum += v; sq += v * v;
    }
    ((float2*)part)[(bb * 8 + chunk) * D_ + d] = make_float2(sum, sq);
}

__global__ __launch_bounds__(256)
void in_stats_combine(const float* __restrict__ part, float* __restrict__ stats)
{
    int bd = blockIdx.x * 256 + threadIdx.x;
    if (bd >= B_ * D_) return;
    int bb = bd / D_, d = bd % D_;
    float sum = 0.f, sq = 0.f;
    const float2* pp = (const float2*)part;
    for (int c = 0; c < 8; c++) {
        float2 v = pp[(bb * 8 + c) * D_ + d];
        sum += v.x; sq += v.y;
    }
    const float invS = 1.f / (float)S_;
    float mu = sum * invS;
    float var = sq * invS - mu * mu;
    ((float2*)stats)[bd] = make_float2(mu, rsqrtf(var + 1e-5f));
}

template<int DUAL>
__global__ __launch_bounds__(256)
void in_apply(const float* __restrict__ a, const float* __restrict__ b2p,
              const float* __restrict__ stats, const float* __restrict__ w,
              const float* __restrict__ bias, float* __restrict__ outp,
              ushort_t* __restrict__ outb)
{
    size_t i4 = (size_t)blockIdx.x * 256 + threadIdx.x;
    int dq = (int)(i4 & 31);
    int bidx = (int)((i4 >> 5) / S_);
    float4 v = ((const float4*)a)[i4];
    if (b2p) {
        float4 u = ((const float4*)b2p)[i4];
        v.x += u.x; v.y += u.y; v.z += u.z; v.w += u.w;
    }
    const float2* st = (const float2*)stats;
    int d0 = dq * 4;
    float2 s0 = st[bidx * D_ + d0 + 0];
    float2 s1 = st[bidx * D_ + d0 + 1];
    float2 s2 = st[bidx * D_ + d0 + 2];
    float2 s3 = st[bidx * D_ + d0 + 3];
    float4 r;
    r.x = (v.x - s0.x) * s0.y * w[d0 + 0] + bias[d0 + 0];
    r.y = (v.y - s1.x) * s1.y * w[d0 + 1] + bias[d0 + 1];
    r.z = (v.z - s2.x) * s2.y * w[d0 + 2] + bias[d0 + 2];
    r.w = (v.w - s3.x) * s3.y * w[d0 + 3] + bias[d0 + 3];
    ((float4*)outp)[i4] = r;
    if (DUAL) {
        ushort4 ub; ub.x = f2bf(r.x); ub.y = f2bf(r.y); ub.z = f2bf(r.z); ub.w = f2bf(r.w);
        ((ushort4*)outb)[i4] = ub;
    }
}

// ---------------------------------------------------------------------------
// Gating (unchanged, reads f32 h)
// ---------------------------------------------------------------------------
__global__ __launch_bounds__(256)
void gate_kernel(const float* __restrict__ h, const float* __restrict__ wg,
                 float* __restrict__ gates)
{
    __shared__ float wgs[D_ * E_];
    for (int i = threadIdx.x; i < D_ * E_; i += 256) wgs[i] = wg[i];
    __syncthreads();
    int t = blockIdx.x * 256 + threadIdx.x;
    const float4* hp = (const float4*)(h + (size_t)t * D_);
    float a0 = 0.f, a1 = 0.f, a2 = 0.f, a3 = 0.f;
    #pragma unroll 8
    for (int dq = 0; dq < 32; dq++) {
        float4 xv = hp[dq];
        const float* w0 = &wgs[dq * 16];
        a0 += xv.x*w0[0] + xv.y*w0[4] + xv.z*w0[8]  + xv.w*w0[12];
        a1 += xv.x*w0[1] + xv.y*w0[5] + xv.z*w0[9]  + xv.w*w0[13];
        a2 += xv.x*w0[2] + xv.y*w0[6] + xv.z*w0[10] + xv.w*w0[14];
        a3 += xv.x*w0[3] + xv.y*w0[7] + xv.z*w0[11] + xv.w*w0[15];
    }
    float lv[4] = {a0, a1, a2, a3};
    int i0 = 0; float m0 = lv[0];
    #pragma unroll
    for (int k = 1; k < 4; k++) if (lv[k] > m0) { m0 = lv[k]; i0 = k; }
    int i1 = -1; float m1 = -1e30f;
    #pragma unroll
    for (int k = 0; k < 4; k++) {
        if (k == i0) continue;
        if (lv[k] > m1) { m1 = lv[k]; i1 = k; }
    }
    float te = __expf(m1 - m0);
    float g0 = 1.f / (1.f + te);
    float g1 = te * g0;
    float g[4] = {0.f, 0.f, 0.f, 0.f};
    g[i0] = g0; g[i1] = g1;
    *(float4*)&gates[(size_t)t * E_] = make_float4(g[0], g[1], g[2], g[3]);
}

// ---------------------------------------------------------------------------
// Launch
// ---------------------------------------------------------------------------
extern "C" void kernel_launch(void* const* d_in, const int* in_sizes, int n_in,
                              void* d_out, int out_size, void* d_ws, size_t ws_size,
                              hipStream_t stream)
{
    const float* x    = (const float*)d_in[0];
    const float* Wqkv = (const float*)d_in[1];
    const float* bqkv = (const float*)d_in[2];
    const float* Wo   = (const float*)d_in[3];
    const float* bo   = (const float*)d_in[4];
    const float* n1w  = (const float*)d_in[5];
    const float* n1b  = (const float*)d_in[6];
    const float* n2w  = (const float*)d_in[7];
    const float* n2b  = (const float*)d_in[8];
    const float* wg   = (const float*)d_in[9];
    const float* W1   = (const float*)d_in[10];
    const float* b1   = (const float*)d_in[11];
    const float* W2   = (const float*)d_in[12];
    const float* b2   = (const float*)d_in[13];

    // Workspace layout (~41.3 MB). t/h/hb reuse the dead qkv region.
    char* ws = (char*)d_ws;
    float*    qkv    = (float*)(ws);                             // 12 MB
    float*    part   = (float*)(ws + 12582912);                  // 10 MB
    ushort_t* attno  = (ushort_t*)(ws + 23068672);               // 2 MB
    float*    t      = (float*)(ws);                             // 4 MB (reuse)
    float*    h      = (float*)(ws + 4194304);                   // 4 MB
    ushort_t* hb     = (ushort_t*)(ws + 8388608);                // 2 MB
    float*    y      = (float*)(ws + 25165824);                  // 4 MB
    ushort_t* hid    = (ushort_t*)(ws + 29360128);               // 8 MB
    ushort_t* xb     = (ushort_t*)(ws + 37748736);               // 2 MB
    ushort_t* Wqkv_t = (ushort_t*)(ws + 39845888);
    ushort_t* Wo_t   = (ushort_t*)(ws + 39944192);
    ushort_t* W1t    = (ushort_t*)(ws + 39976960);
    ushort_t* W2t    = (ushort_t*)(ws + 40501248);
    float*    gates  = (float*)(ws + 41025536);
    float*    pstat  = (float*)(ws + 41156608);
    float*    stats  = (float*)(ws + 41222144);

    dim3 blk(256);

    // 0. bf16 conversions + weight transposes
    prep<<<dim3(1024, 5), blk, 0, stream>>>(x, Wqkv, Wo, W1, W2,
                                            xb, Wqkv_t, Wo_t, W1t, W2t);
    // 1. QKV projection (f32 out for attention)
    gemm_mfma<0, 0><<<dim3(128, 6), dim3(64), 0, stream>>>(
        xb, Wqkv_t, bqkv, nullptr, nullptr, 0, qkv, NTOK, 3 * D_, D_);
    // 2. attention (split over 2 key-chunks) + combine -> bf16
    attn_part<<<dim3(64, 4, 2), blk, 0, stream>>>(qkv, part);
    attn_combine<<<dim3(256), blk, 0, stream>>>(part, attno);
    // 3. out-proj + bias + residual(x) -> t (f32)
    gemm_mfma<1, 0><<<dim3(128, 2), dim3(64), 0, stream>>>(
        attno, Wo_t, bo, x, nullptr, 0, t, NTOK, D_, D_);
    // 4. InstanceNorm 1 -> h (f32) + hb (bf16)
    in_stats_partial<<<dim3(B_, 8), dim3(128), 0, stream>>>(t, nullptr, pstat);
    in_stats_combine<<<dim3(4), blk, 0, stream>>>(pstat, stats);
    in_apply<1><<<dim3(1024), blk, 0, stream>>>(t, nullptr, stats, n1w, n1b, h, hb);
    // 5. gating
    gate_kernel<<<dim3(NTOK / 256), blk, 0, stream>>>(h, wg, gates);
    // 6. MoE FFN (dense; sequential experts to avoid accumulate races)
    hipMemsetAsync(y, 0, (size_t)NTOK * D_ * sizeof(float), stream);
    for (int e = 0; e < E_; e++) {
        gemm_mfma<2, 1><<<dim3(128, 8), dim3(64), 0, stream>>>(
            hb, W1t + (size_t)e * HFF_ * D_, b1 + e * HFF_, nullptr, nullptr, 0,
            hid, NTOK, HFF_, D_);
        gemm_mfma<3, 0><<<dim3(128, 2), dim3(64), 0, stream>>>(
            hid, W2t + (size_t)e * D_ * HFF_, b2 + e * D_, nullptr, gates, e,
            y, NTOK, D_, HFF_);
    }
    // 7. InstanceNorm 2 over (y + h) -> d_out
    in_stats_partial<<<dim3(B_, 8), dim3(128), 0, stream>>>(y, h, pstat);
    in_stats_combine<<<dim3(4), blk, 0, stream>>>(pstat, stats);
    in_apply<0><<<dim3(1024), blk, 0, stream>>>(y, h, stats, n2w, n2b, (float*)d_out, nullptr);
}

// Round 3
// 229.478 us; speedup vs baseline: 2.4101x; 1.4001x over previous
//
#include <hip/hip_runtime.h>
#include <hip/hip_bf16.h>

#define B_   8
#define S_   1024
#define D_   128
#define NH_  8
#define HD_  16
#define E_   4
#define HFF_ 512
#define NTOK (B_*S_)

typedef unsigned short ushort_t;
typedef __attribute__((ext_vector_type(8))) short bf16x8;
typedef __attribute__((ext_vector_type(4))) float f32x4;
typedef __attribute__((ext_vector_type(4))) _Float16 f16x4;

static __device__ __forceinline__ ushort_t f2bf(float f) {
    union { float f; unsigned u; } v; v.f = f;
    unsigned r = v.u + 0x7FFF + ((v.u >> 16) & 1);   // RNE
    return (ushort_t)(r >> 16);
}

// ---------------------------------------------------------------------------
// prep: convert x to bf16 (linear) and all weights to bf16 TRANSPOSED [N][K]
// grid (1024, 5)
// ---------------------------------------------------------------------------
__global__ __launch_bounds__(256)
void prep(const float* __restrict__ x, const float* __restrict__ Wqkv,
          const float* __restrict__ Wo, const float* __restrict__ W1,
          const float* __restrict__ W2,
          ushort_t* __restrict__ xb, ushort_t* __restrict__ Wqkv_t,
          ushort_t* __restrict__ Wo_t, ushort_t* __restrict__ W1t,
          ushort_t* __restrict__ W2t)
{
    const int seg = blockIdx.y;
    const int i = blockIdx.x * 256 + threadIdx.x;
    if (seg == 0) {                       // x: 1048576 elems, 4/thread
        float4 v = ((const float4*)x)[i];
        ushort4 u; u.x = f2bf(v.x); u.y = f2bf(v.y); u.z = f2bf(v.z); u.w = f2bf(v.w);
        ((ushort4*)xb)[i] = u;
    } else if (seg == 1) {                // Wqkv [128][384] -> [384][128]
        if (i < D_ * 3 * D_) {
            int r = i / (3 * D_), c = i % (3 * D_);
            Wqkv_t[c * D_ + r] = f2bf(Wqkv[i]);
        }
    } else if (seg == 2) {                // Wo [128][128] -> T
        if (i < D_ * D_) {
            int r = i >> 7, c = i & 127;
            Wo_t[c * D_ + r] = f2bf(Wo[i]);
        }
    } else if (seg == 3) {                // W1 [4][128][512] -> [4][512][128]
        int e = i >> 16, rem = i & 65535, r = rem >> 9, c = rem & 511;
        W1t[e * 65536 + c * 128 + r] = f2bf(W1[i]);
    } else {                              // W2 [4][512][128] -> [4][128][512]
        int e = i >> 16, rem = i & 65535, r = rem >> 7, c = rem & 127;
        W2t[e * 65536 + c * 512 + r] = f2bf(W2[i]);
    }
}

// ---------------------------------------------------------------------------
// MFMA bf16 GEMM: C[M,N] = A[M,K] @ Bt[N,K]^T + bias, 64x64 tile, 1 wave.
// MODE 0: C = .. + bias            (f32 or bf16 out per OUTBF)
// MODE 1: C = .. + bias + extra    (f32 residual)
// MODE 2: C = relu(.. + bias)
// MODE 3: C += gates[row*E+ge] * (.. + bias)   (f32, pre-zeroed)
// MODE 4: pack to fp16 Q/K/V [b][h][s][16]; Q scaled by 0.25*log2(e)
// ---------------------------------------------------------------------------
template<int MODE, int OUTBF>
__global__ __launch_bounds__(64)
void gemm_mfma(const ushort_t* __restrict__ A, const ushort_t* __restrict__ Bt,
               const float* __restrict__ bias, const float* __restrict__ extra,
               const float* __restrict__ gates, int ge,
               void* __restrict__ Cout, int M, int N, int K,
               _Float16* __restrict__ pq, _Float16* __restrict__ pk,
               _Float16* __restrict__ pv)
{
    __shared__ __align__(16) ushort_t As[4][64][8];   // [k-chunk][m][8k]
    __shared__ __align__(16) ushort_t Bs[4][64][8];   // [k-chunk][n][8k]
    const int bm = blockIdx.x * 64;
    const int bn = blockIdx.y * 64;
    const int l = threadIdx.x;
    const int lc = l & 15, lg = l >> 4;

    f32x4 acc[4][4] = {};

    const ushort_t* ap = A + (size_t)(bm + l) * K;
    const ushort_t* bp = Bt + (size_t)(bn + l) * K;

    for (int k0 = 0; k0 < K; k0 += 32) {
        #pragma unroll
        for (int c = 0; c < 4; c++) {
            *(bf16x8*)As[c][l] = *(const bf16x8*)(ap + k0 + c * 8);
            *(bf16x8*)Bs[c][l] = *(const bf16x8*)(bp + k0 + c * 8);
        }
        __syncthreads();
        bf16x8 af[4], bfr[4];
        #pragma unroll
        for (int f = 0; f < 4; f++) {
            af[f]  = *(const bf16x8*)As[lg][f * 16 + lc];
            bfr[f] = *(const bf16x8*)Bs[lg][f * 16 + lc];
        }
        #pragma unroll
        for (int fm = 0; fm < 4; fm++)
            #pragma unroll
            for (int fn = 0; fn < 4; fn++)
                acc[fm][fn] = __builtin_amdgcn_mfma_f32_16x16x32_bf16(
                    af[fm], bfr[fn], acc[fm][fn], 0, 0, 0);
        __syncthreads();
    }

    // C/D layout (verified): col = lane&15, row = (lane>>4)*4 + reg
    #pragma unroll
    for (int fm = 0; fm < 4; fm++) {
        #pragma unroll
        for (int r = 0; r < 4; r++) {
            const int row = bm + fm * 16 + lg * 4 + r;
            float g = 0.f;
            if (MODE == 3) g = gates[(size_t)row * E_ + ge];
            #pragma unroll
            for (int fn = 0; fn < 4; fn++) {
                const int col = bn + fn * 16 + lc;
                float v = acc[fm][fn][r] + bias[col];
                if (MODE == 4) {
                    // row = token, col -> (part, head, d)
                    const int b = row >> 10, s = row & 1023;
                    const int part = col >> 7, hh = (col >> 4) & 7, dd = col & 15;
                    _Float16* dst = (part == 0) ? pq : (part == 1) ? pk : pv;
                    float sc = (part == 0) ? 0.36067376022224085f : 1.f; // 0.25*log2e
                    dst[(((size_t)(b * NH_ + hh) << 10) + s) * HD_ + dd] = (_Float16)(v * sc);
                    continue;
                }
                const size_t off = (size_t)row * N + col;
                if (MODE == 1) v += extra[off];
                if (MODE == 2) v = fmaxf(v, 0.f);
                if (MODE == 3) {
                    ((float*)Cout)[off] += g * v;
                } else if (OUTBF) {
                    ((ushort_t*)Cout)[off] = f2bf(v);
                } else {
                    ((float*)Cout)[off] = v;
                }
            }
        }
    }
}

// ---------------------------------------------------------------------------
// MFMA flash attention, no LDS. grid (B*NH, 8), block 256 (4 waves).
// Each wave: 32 q rows (2 qtiles of 16). Loop 64 k-tiles of 16.
//  S^T = mfma(A=K, B=Q): lane holds q = lane&15, k = (lane>>4)*4+reg  -> m,l lane-local
//  O^T = mfma(A=V^T, B=P^T): P^T B-frag == S^T layout (no cross-lane moves)
// Scores already carry 0.25*log2e (folded into Q at pack) -> use exp2.
// ---------------------------------------------------------------------------
__global__ __launch_bounds__(256)
void attn_mfma(const _Float16* __restrict__ Qb, const _Float16* __restrict__ Kb,
               const _Float16* __restrict__ Vb, ushort_t* __restrict__ attno)
{
    const int bh = blockIdx.x;
    const int wv = threadIdx.x >> 6;
    const int l  = threadIdx.x & 63;
    const int r = l & 15, g = l >> 4;
    const int q0 = blockIdx.y * 128 + wv * 32;

    const _Float16* qp = Qb + ((size_t)bh << 14);
    const _Float16* kp = Kb + ((size_t)bh << 14);
    const _Float16* vp = Vb + ((size_t)bh << 14);

    f16x4 qf0 = *(const f16x4*)&qp[(q0 + r) * HD_ + g * 4];
    f16x4 qf1 = *(const f16x4*)&qp[(q0 + 16 + r) * HD_ + g * 4];

    f32x4 o0 = {}, o1 = {};
    float m0 = -1e30f, m1 = -1e30f, l0 = 0.f, l1 = 0.f;

    for (int kt = 0; kt < 64; ++kt) {
        f16x4 kf = *(const f16x4*)&kp[(kt * 16 + r) * HD_ + g * 4];
        f32x4 z = {};
        f32x4 s0 = __builtin_amdgcn_mfma_f32_16x16x16f16(kf, qf0, z, 0, 0, 0);
        f32x4 s1 = __builtin_amdgcn_mfma_f32_16x16x16f16(kf, qf1, z, 0, 0, 0);

        f16x4 vf;
        vf[0] = vp[(kt * 16 + g * 4 + 0) * HD_ + r];
        vf[1] = vp[(kt * 16 + g * 4 + 1) * HD_ + r];
        vf[2] = vp[(kt * 16 + g * 4 + 2) * HD_ + r];
        vf[3] = vp[(kt * 16 + g * 4 + 3) * HD_ + r];

        // ---- qtile 0 ----
        {
            float tm = fmaxf(fmaxf(s0[0], s0[1]), fmaxf(s0[2], s0[3]));
            tm = fmaxf(tm, __shfl_xor(tm, 16));
            tm = fmaxf(tm, __shfl_xor(tm, 32));
            float mn = fmaxf(m0, tm);
            float al = exp2f(m0 - mn);
            float p0 = exp2f(s0[0] - mn), p1 = exp2f(s0[1] - mn);
            float p2 = exp2f(s0[2] - mn), p3 = exp2f(s0[3] - mn);
            float ts = (p0 + p1) + (p2 + p3);
            ts += __shfl_xor(ts, 16);
            ts += __shfl_xor(ts, 32);
            l0 = l0 * al + ts;
            o0 *= al;
            m0 = mn;
            f16x4 pf;
            pf[0] = (_Float16)p0; pf[1] = (_Float16)p1;
            pf[2] = (_Float16)p2; pf[3] = (_Float16)p3;
            o0 = __builtin_amdgcn_mfma_f32_16x16x16f16(vf, pf, o0, 0, 0, 0);
        }
        // ---- qtile 1 ----
        {
            float tm = fmaxf(fmaxf(s1[0], s1[1]), fmaxf(s1[2], s1[3]));
            tm = fmaxf(tm, __shfl_xor(tm, 16));
            tm = fmaxf(tm, __shfl_xor(tm, 32));
            float mn = fmaxf(m1, tm);
            float al = exp2f(m1 - mn);
            float p0 = exp2f(s1[0] - mn), p1 = exp2f(s1[1] - mn);
            float p2 = exp2f(s1[2] - mn), p3 = exp2f(s1[3] - mn);
            float ts = (p0 + p1) + (p2 + p3);
            ts += __shfl_xor(ts, 16);
            ts += __shfl_xor(ts, 32);
            l1 = l1 * al + ts;
            o1 *= al;
            m1 = mn;
            f16x4 pf;
            pf[0] = (_Float16)p0; pf[1] = (_Float16)p1;
            pf[2] = (_Float16)p2; pf[3] = (_Float16)p3;
            o1 = __builtin_amdgcn_mfma_f32_16x16x16f16(vf, pf, o1, 0, 0, 0);
        }
    }

    // O^T: lane holds q = r, d = g*4 + reg; l0/l1 lane-local for q=r.
    const int b = bh >> 3, h = bh & 7;
    float inv0 = 1.f / l0, inv1 = 1.f / l1;
    ushort_t* op0 = attno + ((size_t)(b * S_ + q0 + r)) * D_ + h * HD_ + g * 4;
    ushort_t* op1 = attno + ((size_t)(b * S_ + q0 + 16 + r)) * D_ + h * HD_ + g * 4;
    #pragma unroll
    for (int i = 0; i < 4; i++) {
        op0[i] = f2bf(o0[i] * inv0);
        op1[i] = f2bf(o1[i] * inv1);
    }
}

// ---------------------------------------------------------------------------
// InstanceNorm over sequence axis (per (b,d) channel)
// ---------------------------------------------------------------------------
__global__ __launch_bounds__(128)
void in_stats_partial(const float* __restrict__ a, const float* __restrict__ b2p,
                      float* __restrict__ part)
{
    const int bb = blockIdx.x, chunk = blockIdx.y, d = threadIdx.x;
    const size_t base = (size_t)bb * S_ * D_ + (size_t)chunk * (S_ / 8) * D_ + d;
    float sum = 0.f, sq = 0.f;
    for (int s = 0; s < S_ / 8; s++) {
        float v = a[base + (size_t)s * D_];
        if (b2p) v += b2p[base + (size_t)s * D_];
        sum += v; sq += v * v;
    }
    ((float2*)part)[(bb * 8 + chunk) * D_ + d] = make_float2(sum, sq);
}

__global__ __launch_bounds__(256)
void in_stats_combine(const float* __restrict__ part, float* __restrict__ stats)
{
    int bd = blockIdx.x * 256 + threadIdx.x;
    if (bd >= B_ * D_) return;
    int bb = bd / D_, d = bd % D_;
    float sum = 0.f, sq = 0.f;
    const float2* pp = (const float2*)part;
    for (int c = 0; c < 8; c++) {
        float2 v = pp[(bb * 8 + c) * D_ + d];
        sum += v.x; sq += v.y;
    }
    const float invS = 1.f / (float)S_;
    float mu = sum * invS;
    float var = sq * invS - mu * mu;
    ((float2*)stats)[bd] = make_float2(mu, rsqrtf(var + 1e-5f));
}

template<int DUAL>
__global__ __launch_bounds__(256)
void in_apply(const float* __restrict__ a, const float* __restrict__ b2p,
              const float* __restrict__ stats, const float* __restrict__ w,
              const float* __restrict__ bias, float* __restrict__ outp,
              ushort_t* __restrict__ outb)
{
    size_t i4 = (size_t)blockIdx.x * 256 + threadIdx.x;
    int dq = (int)(i4 & 31);
    int bidx = (int)((i4 >> 5) / S_);
    float4 v = ((const float4*)a)[i4];
    if (b2p) {
        float4 u = ((const float4*)b2p)[i4];
        v.x += u.x; v.y += u.y; v.z += u.z; v.w += u.w;
    }
    const float2* st = (const float2*)stats;
    int d0 = dq * 4;
    float2 s0 = st[bidx * D_ + d0 + 0];
    float2 s1 = st[bidx * D_ + d0 + 1];
    float2 s2 = st[bidx * D_ + d0 + 2];
    float2 s3 = st[bidx * D_ + d0 + 3];
    float4 r;
    r.x = (v.x - s0.x) * s0.y * w[d0 + 0] + bias[d0 + 0];
    r.y = (v.y - s1.x) * s1.y * w[d0 + 1] + bias[d0 + 1];
    r.z = (v.z - s2.x) * s2.y * w[d0 + 2] + bias[d0 + 2];
    r.w = (v.w - s3.x) * s3.y * w[d0 + 3] + bias[d0 + 3];
    ((float4*)outp)[i4] = r;
    if (DUAL) {
        ushort4 ub; ub.x = f2bf(r.x); ub.y = f2bf(r.y); ub.z = f2bf(r.z); ub.w = f2bf(r.w);
        ((ushort4*)outb)[i4] = ub;
    }
}

// ---------------------------------------------------------------------------
// Gating
// ---------------------------------------------------------------------------
__global__ __launch_bounds__(256)
void gate_kernel(const float* __restrict__ h, const float* __restrict__ wg,
                 float* __restrict__ gates)
{
    __shared__ float wgs[D_ * E_];
    for (int i = threadIdx.x; i < D_ * E_; i += 256) wgs[i] = wg[i];
    __syncthreads();
    int t = blockIdx.x * 256 + threadIdx.x;
    const float4* hp = (const float4*)(h + (size_t)t * D_);
    float a0 = 0.f, a1 = 0.f, a2 = 0.f, a3 = 0.f;
    #pragma unroll 8
    for (int dq = 0; dq < 32; dq++) {
        float4 xv = hp[dq];
        const float* w0 = &wgs[dq * 16];
        a0 += xv.x*w0[0] + xv.y*w0[4] + xv.z*w0[8]  + xv.w*w0[12];
        a1 += xv.x*w0[1] + xv.y*w0[5] + xv.z*w0[9]  + xv.w*w0[13];
        a2 += xv.x*w0[2] + xv.y*w0[6] + xv.z*w0[10] + xv.w*w0[14];
        a3 += xv.x*w0[3] + xv.y*w0[7] + xv.z*w0[11] + xv.w*w0[15];
    }
    float lv[4] = {a0, a1, a2, a3};
    int i0 = 0; float m0 = lv[0];
    #pragma unroll
    for (int k = 1; k < 4; k++) if (lv[k] > m0) { m0 = lv[k]; i0 = k; }
    int i1 = -1; float m1 = -1e30f;
    #pragma unroll
    for (int k = 0; k < 4; k++) {
        if (k == i0) continue;
        if (lv[k] > m1) { m1 = lv[k]; i1 = k; }
    }
    float te = __expf(m1 - m0);
    float g0 = 1.f / (1.f + te);
    float g1 = te * g0;
    float g[4] = {0.f, 0.f, 0.f, 0.f};
    g[i0] = g0; g[i1] = g1;
    *(float4*)&gates[(size_t)t * E_] = make_float4(g[0], g[1], g[2], g[3]);
}

// ---------------------------------------------------------------------------
// Launch
// ---------------------------------------------------------------------------
extern "C" void kernel_launch(void* const* d_in, const int* in_sizes, int n_in,
                              void* d_out, int out_size, void* d_ws, size_t ws_size,
                              hipStream_t stream)
{
    const float* x    = (const float*)d_in[0];
    const float* Wqkv = (const float*)d_in[1];
    const float* bqkv = (const float*)d_in[2];
    const float* Wo   = (const float*)d_in[3];
    const float* bo   = (const float*)d_in[4];
    const float* n1w  = (const float*)d_in[5];
    const float* n1b  = (const float*)d_in[6];
    const float* n2w  = (const float*)d_in[7];
    const float* n2b  = (const float*)d_in[8];
    const float* wg   = (const float*)d_in[9];
    const float* W1   = (const float*)d_in[10];
    const float* b1   = (const float*)d_in[11];
    const float* W2   = (const float*)d_in[12];
    const float* b2   = (const float*)d_in[13];

    // Workspace layout (~34 MB)
    char* ws = (char*)d_ws;
    _Float16* Qb     = (_Float16*)(ws);                          // 2 MB
    _Float16* Kb     = (_Float16*)(ws + (2u << 20));             // 2 MB
    _Float16* Vb     = (_Float16*)(ws + (4u << 20));             // 2 MB
    ushort_t* attno  = (ushort_t*)(ws + (6u << 20));             // 2 MB
    float*    t      = (float*)(ws + (8u << 20));                // 4 MB
    float*    h      = (float*)(ws + (12u << 20));               // 4 MB
    ushort_t* hb     = (ushort_t*)(ws + (16u << 20));            // 2 MB
    float*    y      = (float*)(ws + (18u << 20));               // 4 MB
    ushort_t* hid    = (ushort_t*)(ws + (22u << 20));            // 8 MB
    ushort_t* xb     = (ushort_t*)(ws + (30u << 20));            // 2 MB
    char*     wbase  = ws + (32u << 20);
    ushort_t* Wqkv_t = (ushort_t*)(wbase);                       // 96 KB
    ushort_t* Wo_t   = (ushort_t*)(wbase + (128u << 10));        // 32 KB
    ushort_t* W1t    = (ushort_t*)(wbase + (192u << 10));        // 512 KB
    ushort_t* W2t    = (ushort_t*)(wbase + (704u << 10));        // 512 KB
    float*    gates  = (float*)(wbase + (1216u << 10));          // 128 KB
    float*    pstat  = (float*)(wbase + (1344u << 10));          // 64 KB
    float*    stats  = (float*)(wbase + (1408u << 10));          // 8 KB

    dim3 blk(256);

    // 0. bf16 conversions + weight transposes
    prep<<<dim3(1024, 5), blk, 0, stream>>>(x, Wqkv, Wo, W1, W2,
                                            xb, Wqkv_t, Wo_t, W1t, W2t);
    // 1. QKV projection, fused fp16 head-pack (MODE 4)
    gemm_mfma<4, 0><<<dim3(128, 6), dim3(64), 0, stream>>>(
        xb, Wqkv_t, bqkv, nullptr, nullptr, 0, nullptr, NTOK, 3 * D_, D_,
        Qb, Kb, Vb);
    // 2. MFMA flash attention -> attno (bf16)
    attn_mfma<<<dim3(64, 8), blk, 0, stream>>>(Qb, Kb, Vb, attno);
    // 3. out-proj + bias + residual(x) -> t (f32)
    gemm_mfma<1, 0><<<dim3(128, 2), dim3(64), 0, stream>>>(
        attno, Wo_t, bo, x, nullptr, 0, t, NTOK, D_, D_, nullptr, nullptr, nullptr);
    // 4. InstanceNorm 1 -> h (f32) + hb (bf16)
    in_stats_partial<<<dim3(B_, 8), dim3(128), 0, stream>>>(t, nullptr, pstat);
    in_stats_combine<<<dim3(4), blk, 0, stream>>>(pstat, stats);
    in_apply<1><<<dim3(1024), blk, 0, stream>>>(t, nullptr, stats, n1w, n1b, h, hb);
    // 5. gating
    gate_kernel<<<dim3(NTOK / 256), blk, 0, stream>>>(h, wg, gates);
    // 6. MoE FFN
    hipMemsetAsync(y, 0, (size_t)NTOK * D_ * sizeof(float), stream);
    for (int e = 0; e < E_; e++) {
        gemm_mfma<2, 1><<<dim3(128, 8), dim3(64), 0, stream>>>(
            hb, W1t + (size_t)e * HFF_ * D_, b1 + e * HFF_, nullptr, nullptr, 0,
            hid, NTOK, HFF_, D_, nullptr, nullptr, nullptr);
        gemm_mfma<3, 0><<<dim3(128, 2), dim3(64), 0, stream>>>(
            hid, W2t + (size_t)e * D_ * HFF_, b2 + e * D_, nullptr, gates, e,
            y, NTOK, D_, HFF_, nullptr, nullptr, nullptr);
    }
    // 7. InstanceNorm 2 over (y + h) -> d_out
    in_stats_partial<<<dim3(B_, 8), dim3(128), 0, stream>>>(y, h, pstat);
    in_stats_combine<<<dim3(4), blk, 0, stream>>>(pstat, stats);
    in_apply<0><<<dim3(1024), blk, 0, stream>>>(y, h, stats, n2w, n2b, (float*)d_out, nullptr);
}

// Round 4
// 183.752 us; speedup vs baseline: 3.0098x; 1.2488x over previous
//
#include <hip/hip_runtime.h>
#include <hip/hip_bf16.h>

#define B_   8
#define S_   1024
#define D_   128
#define NH_  8
#define HD_  16
#define E_   4
#define HFF_ 512
#define NTOK (B_*S_)

typedef unsigned short ushort_t;
typedef __attribute__((ext_vector_type(8))) short bf16x8;
typedef __attribute__((ext_vector_type(4))) float f32x4;
typedef __attribute__((ext_vector_type(4))) _Float16 f16x4;

static __device__ __forceinline__ ushort_t f2bf(float f) {
    union { float f; unsigned u; } v; v.f = f;
    unsigned r = v.u + 0x7FFF + ((v.u >> 16) & 1);   // RNE
    return (ushort_t)(r >> 16);
}

// ---------------------------------------------------------------------------
// prep: x -> bf16; weights -> bf16 transposed layouts.
//   Wqkv_t [384][128], Wo_t [128][128], W1t [4][512][128] (B^T per expert),
//   W2t2 [128][2048]  (fused-K layout: W2t2[d][e*512+h] = W2[e][h][d])
// grid (1024, 5)
// ---------------------------------------------------------------------------
__global__ __launch_bounds__(256)
void prep(const float* __restrict__ x, const float* __restrict__ Wqkv,
          const float* __restrict__ Wo, const float* __restrict__ W1,
          const float* __restrict__ W2,
          ushort_t* __restrict__ xb, ushort_t* __restrict__ Wqkv_t,
          ushort_t* __restrict__ Wo_t, ushort_t* __restrict__ W1t,
          ushort_t* __restrict__ W2t2)
{
    const int seg = blockIdx.y;
    const int i = blockIdx.x * 256 + threadIdx.x;
    if (seg == 0) {                       // x: 1048576 elems, 4/thread
        float4 v = ((const float4*)x)[i];
        ushort4 u; u.x = f2bf(v.x); u.y = f2bf(v.y); u.z = f2bf(v.z); u.w = f2bf(v.w);
        ((ushort4*)xb)[i] = u;
    } else if (seg == 1) {                // Wqkv [128][384] -> [384][128]
        if (i < D_ * 3 * D_) {
            int r = i / (3 * D_), c = i % (3 * D_);
            Wqkv_t[c * D_ + r] = f2bf(Wqkv[i]);
        }
    } else if (seg == 2) {                // Wo [128][128] -> T
        if (i < D_ * D_) {
            int r = i >> 7, c = i & 127;
            Wo_t[c * D_ + r] = f2bf(Wo[i]);
        }
    } else if (seg == 3) {                // W1 [4][128][512] -> [4][512][128]
        int e = i >> 16, rem = i & 65535, r = rem >> 9, c = rem & 511;
        W1t[e * 65536 + c * 128 + r] = f2bf(W1[i]);
    } else {                              // W2 [4][512][128] -> [128][2048]
        int e = i >> 16, rem = i & 65535, hh = rem >> 7, dd = rem & 127;
        W2t2[dd * 2048 + e * 512 + hh] = f2bf(W2[i]);
    }
}

// ---------------------------------------------------------------------------
// 128x128-tile bf16 MFMA GEMM, 256 threads = 4 waves (2x2), 4x4 frags/wave.
// C[M,N] = A[M,K] @ Bt[N,K]^T  (+ mode-specific epilogue)
// MODE 0: QKV: pack fp16 Q/K (scaled Q) [bh][s][16] and V^T [bh][d][s]
// MODE 1: f32 out = acc + bias[col] + extra[row*N+col]          (out-proj)
// MODE 2: W1: e=blockIdx.z; bf16 hid[row][e*512+col] = relu(acc+b1[e,col])*g[row,e]
// MODE 3: W2 fused: f32 yh[row][col] = acc + sum_e g[row,e]*b2[e,col] + extra
// ---------------------------------------------------------------------------
template<int MODE>
__global__ __launch_bounds__(256)
void gemm128(const ushort_t* __restrict__ A, const ushort_t* __restrict__ Bt,
             const float* __restrict__ bias, const float* __restrict__ extra,
             const float* __restrict__ gates,
             void* __restrict__ Cout, int M, int N, int K,
             _Float16* __restrict__ pq, _Float16* __restrict__ pk,
             _Float16* __restrict__ pv)
{
    __shared__ __align__(16) ushort_t As[4][128][8];   // [kchunk][m][8k]
    __shared__ __align__(16) ushort_t Bs[4][128][8];   // [kchunk][n][8k]
    const int bm = blockIdx.x * 128;
    const int bn = blockIdx.y * 128;
    const int e  = (MODE == 2) ? blockIdx.z : 0;
    const int tid = threadIdx.x;
    const int l = tid & 63, wv = tid >> 6;
    const int lc = l & 15, lg = l >> 4;
    const int wr = wv >> 1, wc = wv & 1;

    const ushort_t* Bte = (MODE == 2) ? (Bt + (size_t)e * HFF_ * D_) : Bt;

    f32x4 acc[4][4] = {};

    const int srow = tid & 127, sch = tid >> 7;        // staging: row, chunk{sch, sch+2}
    const ushort_t* ap = A + (size_t)(bm + srow) * K + sch * 8;
    const ushort_t* bp = Bte + (size_t)(bn + srow) * K + sch * 8;

    for (int k0 = 0; k0 < K; k0 += 32) {
        *(bf16x8*)As[sch][srow]     = *(const bf16x8*)(ap + k0);
        *(bf16x8*)As[sch + 2][srow] = *(const bf16x8*)(ap + k0 + 16);
        *(bf16x8*)Bs[sch][srow]     = *(const bf16x8*)(bp + k0);
        *(bf16x8*)Bs[sch + 2][srow] = *(const bf16x8*)(bp + k0 + 16);
        __syncthreads();
        bf16x8 af[4], bfr[4];
        #pragma unroll
        for (int f = 0; f < 4; f++) {
            af[f]  = *(const bf16x8*)As[lg][wr * 64 + f * 16 + lc];
            bfr[f] = *(const bf16x8*)Bs[lg][wc * 64 + f * 16 + lc];
        }
        #pragma unroll
        for (int fm = 0; fm < 4; fm++)
            #pragma unroll
            for (int fn = 0; fn < 4; fn++)
                acc[fm][fn] = __builtin_amdgcn_mfma_f32_16x16x32_bf16(
                    af[fm], bfr[fn], acc[fm][fn], 0, 0, 0);
        __syncthreads();
    }

    // C/D layout: col = lane&15 (+fn*16+wc*64), row = (lane>>4)*4+reg (+fm*16+wr*64)
    #pragma unroll
    for (int fm = 0; fm < 4; fm++) {
        #pragma unroll
        for (int rr = 0; rr < 4; rr++) {
            const int row = bm + wr * 64 + fm * 16 + lg * 4 + rr;
            float gsc = 0.f; float4 g4;
            if (MODE == 2) gsc = gates[(size_t)row * E_ + e];
            if (MODE == 3) g4 = *(const float4*)&gates[(size_t)row * E_];
            #pragma unroll
            for (int fn = 0; fn < 4; fn++) {
                const int col = bn + wc * 64 + fn * 16 + lc;
                float v = acc[fm][fn][rr];
                if (MODE == 0) {
                    v += bias[col];
                    const int b = row >> 10, s = row & 1023;
                    const int part = col >> 7, hh = (col >> 4) & 7, dd = col & 15;
                    const size_t bh = (size_t)(b * NH_ + hh);
                    if (part == 0)
                        pq[(bh * 1024 + s) * HD_ + dd] = (_Float16)(v * 0.36067376022224085f);
                    else if (part == 1)
                        pk[(bh * 1024 + s) * HD_ + dd] = (_Float16)v;
                    else
                        pv[(bh << 14) + (dd << 10) + s] = (_Float16)v;
                } else if (MODE == 1) {
                    const size_t off = (size_t)row * N + col;
                    ((float*)Cout)[off] = v + bias[col] + extra[off];
                } else if (MODE == 2) {
                    v = fmaxf(v + bias[e * HFF_ + col], 0.f) * gsc;
                    ((ushort_t*)Cout)[(size_t)row * 2048 + e * HFF_ + col] = f2bf(v);
                } else {   // MODE 3
                    v += g4.x * bias[col] + g4.y * bias[128 + col]
                       + g4.z * bias[256 + col] + g4.w * bias[384 + col];
                    const size_t off = (size_t)row * 128 + col;
                    ((float*)Cout)[off] = v + extra[off];
                }
            }
        }
    }
}

// ---------------------------------------------------------------------------
// MFMA flash attention, no LDS. grid (B*NH, 8), block 256 (4 waves).
// Wave: 32 q rows (2 qtiles), loop 32 iters x 32 keys (2 ktiles per softmax).
//  S^T = mfma(A=K, B=Q); P^T packs in-register into B-frag of O^T = mfma(V^T, P^T).
//  V stored transposed [bh][d][s] -> vector f16x4 loads.
// Q carries 0.25*log2e -> exp2.
// ---------------------------------------------------------------------------
__global__ __launch_bounds__(256)
void attn_mfma(const _Float16* __restrict__ Qb, const _Float16* __restrict__ Kb,
               const _Float16* __restrict__ Vt, ushort_t* __restrict__ attno)
{
    const int bh = blockIdx.x;
    const int wv = threadIdx.x >> 6;
    const int l  = threadIdx.x & 63;
    const int r = l & 15, g = l >> 4;
    const int q0 = blockIdx.y * 128 + wv * 32;

    const _Float16* qp = Qb + ((size_t)bh << 14);
    const _Float16* kp = Kb + ((size_t)bh << 14);
    const _Float16* vp = Vt + ((size_t)bh << 14);

    f16x4 qf0 = *(const f16x4*)&qp[(q0 + r) * HD_ + g * 4];
    f16x4 qf1 = *(const f16x4*)&qp[(q0 + 16 + r) * HD_ + g * 4];

    f32x4 o0 = {}, o1 = {};
    float m0 = -1e30f, m1 = -1e30f, l0 = 0.f, l1 = 0.f;

    for (int it = 0; it < 32; ++it) {
        const int j0 = it * 32;
        f16x4 kf0 = *(const f16x4*)&kp[(j0 + r) * HD_ + g * 4];
        f16x4 kf1 = *(const f16x4*)&kp[(j0 + 16 + r) * HD_ + g * 4];
        f16x4 vf0 = *(const f16x4*)&vp[r * 1024 + j0 + g * 4];
        f16x4 vf1 = *(const f16x4*)&vp[r * 1024 + j0 + 16 + g * 4];

        f32x4 z = {};
        f32x4 s00 = __builtin_amdgcn_mfma_f32_16x16x16f16(kf0, qf0, z, 0, 0, 0);
        f32x4 s01 = __builtin_amdgcn_mfma_f32_16x16x16f16(kf1, qf0, z, 0, 0, 0);
        f32x4 s10 = __builtin_amdgcn_mfma_f32_16x16x16f16(kf0, qf1, z, 0, 0, 0);
        f32x4 s11 = __builtin_amdgcn_mfma_f32_16x16x16f16(kf1, qf1, z, 0, 0, 0);

        // ---- qtile 0 ----
        {
            float tm = fmaxf(fmaxf(fmaxf(s00[0], s00[1]), fmaxf(s00[2], s00[3])),
                             fmaxf(fmaxf(s01[0], s01[1]), fmaxf(s01[2], s01[3])));
            tm = fmaxf(tm, __shfl_xor(tm, 16));
            tm = fmaxf(tm, __shfl_xor(tm, 32));
            float mn = fmaxf(m0, tm);
            float al = exp2f(m0 - mn);
            m0 = mn;
            float p0 = exp2f(s00[0] - mn), p1 = exp2f(s00[1] - mn);
            float p2 = exp2f(s00[2] - mn), p3 = exp2f(s00[3] - mn);
            float p4 = exp2f(s01[0] - mn), p5 = exp2f(s01[1] - mn);
            float p6 = exp2f(s01[2] - mn), p7 = exp2f(s01[3] - mn);
            float ts = ((p0 + p1) + (p2 + p3)) + ((p4 + p5) + (p6 + p7));
            ts += __shfl_xor(ts, 16);
            ts += __shfl_xor(ts, 32);
            l0 = l0 * al + ts;
            o0 *= al;
            f16x4 pf0, pf1;
            pf0[0] = (_Float16)p0; pf0[1] = (_Float16)p1;
            pf0[2] = (_Float16)p2; pf0[3] = (_Float16)p3;
            pf1[0] = (_Float16)p4; pf1[1] = (_Float16)p5;
            pf1[2] = (_Float16)p6; pf1[3] = (_Float16)p7;
            o0 = __builtin_amdgcn_mfma_f32_16x16x16f16(vf0, pf0, o0, 0, 0, 0);
            o0 = __builtin_amdgcn_mfma_f32_16x16x16f16(vf1, pf1, o0, 0, 0, 0);
        }
        // ---- qtile 1 ----
        {
            float tm = fmaxf(fmaxf(fmaxf(s10[0], s10[1]), fmaxf(s10[2], s10[3])),
                             fmaxf(fmaxf(s11[0], s11[1]), fmaxf(s11[2], s11[3])));
            tm = fmaxf(tm, __shfl_xor(tm, 16));
            tm = fmaxf(tm, __shfl_xor(tm, 32));
            float mn = fmaxf(m1, tm);
            float al = exp2f(m1 - mn);
            m1 = mn;
            float p0 = exp2f(s10[0] - mn), p1 = exp2f(s10[1] - mn);
            float p2 = exp2f(s10[2] - mn), p3 = exp2f(s10[3] - mn);
            float p4 = exp2f(s11[0] - mn), p5 = exp2f(s11[1] - mn);
            float p6 = exp2f(s11[2] - mn), p7 = exp2f(s11[3] - mn);
            float ts = ((p0 + p1) + (p2 + p3)) + ((p4 + p5) + (p6 + p7));
            ts += __shfl_xor(ts, 16);
            ts += __shfl_xor(ts, 32);
            l1 = l1 * al + ts;
            o1 *= al;
            f16x4 pf0, pf1;
            pf0[0] = (_Float16)p0; pf0[1] = (_Float16)p1;
            pf0[2] = (_Float16)p2; pf0[3] = (_Float16)p3;
            pf1[0] = (_Float16)p4; pf1[1] = (_Float16)p5;
            pf1[2] = (_Float16)p6; pf1[3] = (_Float16)p7;
            o1 = __builtin_amdgcn_mfma_f32_16x16x16f16(vf0, pf0, o1, 0, 0, 0);
            o1 = __builtin_amdgcn_mfma_f32_16x16x16f16(vf1, pf1, o1, 0, 0, 0);
        }
    }

    // O^T: lane holds q = r (col), d = g*4 + reg (row)
    const int b = bh >> 3, h = bh & 7;
    float inv0 = 1.f / l0, inv1 = 1.f / l1;
    ushort_t* op0 = attno + ((size_t)(b * S_ + q0 + r)) * D_ + h * HD_ + g * 4;
    ushort_t* op1 = attno + ((size_t)(b * S_ + q0 + 16 + r)) * D_ + h * HD_ + g * 4;
    #pragma unroll
    for (int i = 0; i < 4; i++) {
        op0[i] = f2bf(o0[i] * inv0);
        op1[i] = f2bf(o1[i] * inv1);
    }
}

// ---------------------------------------------------------------------------
// InstanceNorm stats (per (b,d) channel over S). grid (B, 32), 128 thr.
// ---------------------------------------------------------------------------
__global__ __launch_bounds__(128)
void in_stats_partial(const float* __restrict__ a, float* __restrict__ part)
{
    const int bb = blockIdx.x, chunk = blockIdx.y, d = threadIdx.x;
    const size_t base = (size_t)bb * S_ * D_ + (size_t)chunk * (S_ / 32) * D_ + d;
    float sum = 0.f, sq = 0.f;
    #pragma unroll 8
    for (int s = 0; s < S_ / 32; s++) {
        float v = a[base + (size_t)s * D_];
        sum += v; sq += v * v;
    }
    ((float2*)part)[(bb * 32 + chunk) * D_ + d] = make_float2(sum, sq);
}

__global__ __launch_bounds__(256)
void in_stats_combine(const float* __restrict__ part, float* __restrict__ stats)
{
    int bd = blockIdx.x * 256 + threadIdx.x;
    if (bd >= B_ * D_) return;
    int bb = bd >> 7, d = bd & 127;
    float sum = 0.f, sq = 0.f;
    const float2* pp = (const float2*)part;
    for (int c = 0; c < 32; c++) {
        float2 v = pp[(bb * 32 + c) * D_ + d];
        sum += v.x; sq += v.y;
    }
    const float invS = 1.f / (float)S_;
    float mu = sum * invS;
    float var = sq * invS - mu * mu;
    ((float2*)stats)[bd] = make_float2(mu, rsqrtf(var + 1e-5f));
}

// Apply norm; DUAL=1 additionally writes bf16 copy AND computes MoE gates
// (logits via intra-32-lane shuffle reduce; top-2 softmax). grid 1024 x 256.
template<int DUAL>
__global__ __launch_bounds__(256)
void in_apply(const float* __restrict__ a, const float* __restrict__ stats,
              const float* __restrict__ w, const float* __restrict__ bias,
              const float* __restrict__ wg, float* __restrict__ outp,
              ushort_t* __restrict__ outb, float* __restrict__ gates)
{
    size_t i4 = (size_t)blockIdx.x * 256 + threadIdx.x;
    int dq = (int)(i4 & 31);
    int tok = (int)(i4 >> 5);
    int bidx = tok >> 10;
    int d0 = dq * 4;
    float4 v = ((const float4*)a)[i4];
    const float2* st = (const float2*)stats;
    float2 s0 = st[bidx * D_ + d0 + 0];
    float2 s1 = st[bidx * D_ + d0 + 1];
    float2 s2 = st[bidx * D_ + d0 + 2];
    float2 s3 = st[bidx * D_ + d0 + 3];
    float4 r;
    r.x = (v.x - s0.x) * s0.y * w[d0 + 0] + bias[d0 + 0];
    r.y = (v.y - s1.x) * s1.y * w[d0 + 1] + bias[d0 + 1];
    r.z = (v.z - s2.x) * s2.y * w[d0 + 2] + bias[d0 + 2];
    r.w = (v.w - s3.x) * s3.y * w[d0 + 3] + bias[d0 + 3];
    ((float4*)outp)[i4] = r;
    if (DUAL) {
        ushort4 ub; ub.x = f2bf(r.x); ub.y = f2bf(r.y); ub.z = f2bf(r.z); ub.w = f2bf(r.w);
        ((ushort4*)outb)[i4] = ub;
        // gate logits: a_e = sum_d r_d * wg[d][e]
        float rv[4] = {r.x, r.y, r.z, r.w};
        float4 aa = make_float4(0.f, 0.f, 0.f, 0.f);
        #pragma unroll
        for (int j = 0; j < 4; j++) {
            float4 wj = ((const float4*)wg)[d0 + j];
            aa.x += rv[j] * wj.x; aa.y += rv[j] * wj.y;
            aa.z += rv[j] * wj.z; aa.w += rv[j] * wj.w;
        }
        #pragma unroll
        for (int msk = 1; msk <= 16; msk <<= 1) {
            aa.x += __shfl_xor(aa.x, msk);
            aa.y += __shfl_xor(aa.y, msk);
            aa.z += __shfl_xor(aa.z, msk);
            aa.w += __shfl_xor(aa.w, msk);
        }
        if (dq == 0) {
            float lv[4] = {aa.x, aa.y, aa.z, aa.w};
            int i0 = 0; float mm0 = lv[0];
            #pragma unroll
            for (int k = 1; k < 4; k++) if (lv[k] > mm0) { mm0 = lv[k]; i0 = k; }
            int i1 = -1; float mm1 = -1e30f;
            #pragma unroll
            for (int k = 0; k < 4; k++) {
                if (k == i0) continue;
                if (lv[k] > mm1) { mm1 = lv[k]; i1 = k; }
            }
            float te = __expf(mm1 - mm0);
            float g0 = 1.f / (1.f + te);
            float g1 = te * g0;
            float gg[4] = {0.f, 0.f, 0.f, 0.f};
            gg[i0] = g0; gg[i1] = g1;
            *(float4*)&gates[(size_t)tok * E_] = make_float4(gg[0], gg[1], gg[2], gg[3]);
        }
    }
}

// ---------------------------------------------------------------------------
// Launch
// ---------------------------------------------------------------------------
extern "C" void kernel_launch(void* const* d_in, const int* in_sizes, int n_in,
                              void* d_out, int out_size, void* d_ws, size_t ws_size,
                              hipStream_t stream)
{
    const float* x    = (const float*)d_in[0];
    const float* Wqkv = (const float*)d_in[1];
    const float* bqkv = (const float*)d_in[2];
    const float* Wo   = (const float*)d_in[3];
    const float* bo   = (const float*)d_in[4];
    const float* n1w  = (const float*)d_in[5];
    const float* n1b  = (const float*)d_in[6];
    const float* n2w  = (const float*)d_in[7];
    const float* n2b  = (const float*)d_in[8];
    const float* wg   = (const float*)d_in[9];
    const float* W1   = (const float*)d_in[10];
    const float* b1   = (const float*)d_in[11];
    const float* W2   = (const float*)d_in[12];
    const float* b2   = (const float*)d_in[13];

    // Workspace (~45.6 MB). hid [0,32M) overlays early-phase buffers
    // (Qb/Kb/Vt/attno/t), all dead before W1 writes hid.
    char* ws = (char*)d_ws;
    ushort_t* hid    = (ushort_t*)(ws);                          // 32 MB [0,32M)
    _Float16* Qb     = (_Float16*)(ws);                          // 2 MB
    _Float16* Kb     = (_Float16*)(ws + (2u << 20));             // 2 MB
    _Float16* Vt     = (_Float16*)(ws + (4u << 20));             // 2 MB
    ushort_t* attno  = (ushort_t*)(ws + (6u << 20));             // 2 MB
    float*    t      = (float*)(ws + (8u << 20));                // 4 MB
    float*    h      = (float*)(ws + (32u << 20));               // 4 MB
    ushort_t* hb     = (ushort_t*)(ws + (36u << 20));            // 2 MB
    float*    yh     = (float*)(ws + (38u << 20));               // 4 MB
    ushort_t* xb     = (ushort_t*)(ws + (42u << 20));            // 2 MB
    char*     wbase  = ws + (44u << 20);
    ushort_t* Wqkv_t = (ushort_t*)(wbase);                       // 96 KB
    ushort_t* Wo_t   = (ushort_t*)(wbase + (128u << 10));        // 32 KB
    ushort_t* W1t    = (ushort_t*)(wbase + (192u << 10));        // 512 KB
    ushort_t* W2t2   = (ushort_t*)(wbase + (704u << 10));        // 512 KB
    float*    gates  = (float*)(wbase + (1216u << 10));          // 128 KB
    float*    pstat  = (float*)(wbase + (1344u << 10));          // 256 KB
    float*    stats  = (float*)(wbase + (1600u << 10));          // 8 KB

    dim3 blk(256);

    // 0. bf16 conversions + weight transposes
    prep<<<dim3(1024, 5), blk, 0, stream>>>(x, Wqkv, Wo, W1, W2,
                                            xb, Wqkv_t, Wo_t, W1t, W2t2);
    // 1. QKV projection with fused fp16 Q/K/V^T pack
    gemm128<0><<<dim3(64, 3), blk, 0, stream>>>(
        xb, Wqkv_t, bqkv, nullptr, nullptr, nullptr, NTOK, 3 * D_, D_, Qb, Kb, Vt);
    // 2. MFMA flash attention -> attno (bf16)
    attn_mfma<<<dim3(64, 8), blk, 0, stream>>>(Qb, Kb, Vt, attno);
    // 3. out-proj + bias + residual(x) -> t (f32)
    gemm128<1><<<dim3(64, 1), blk, 0, stream>>>(
        attno, Wo_t, bo, x, nullptr, t, NTOK, D_, D_, nullptr, nullptr, nullptr);
    // 4. InstanceNorm 1 -> h (f32) + hb (bf16) + fused gating
    in_stats_partial<<<dim3(B_, 32), dim3(128), 0, stream>>>(t, pstat);
    in_stats_combine<<<dim3(4), blk, 0, stream>>>(pstat, stats);
    in_apply<1><<<dim3(1024), blk, 0, stream>>>(t, stats, n1w, n1b, wg, h, hb, gates);
    // 5. MoE W1 (all experts, gate folded into hid) -> hid [8192][2048] bf16
    gemm128<2><<<dim3(64, 4, 4), blk, 0, stream>>>(
        hb, W1t, b1, nullptr, gates, hid, NTOK, HFF_, D_, nullptr, nullptr, nullptr);
    // 6. MoE W2 as single K=2048 GEMM, epilogue: + sum_e g*b2 + h -> yh (f32)
    gemm128<3><<<dim3(64, 1), blk, 0, stream>>>(
        hid, W2t2, b2, h, gates, yh, NTOK, D_, E_ * HFF_, nullptr, nullptr, nullptr);
    // 7. InstanceNorm 2 over yh -> d_out
    in_stats_partial<<<dim3(B_, 32), dim3(128), 0, stream>>>(yh, pstat);
    in_stats_combine<<<dim3(4), blk, 0, stream>>>(pstat, stats);
    in_apply<0><<<dim3(1024), blk, 0, stream>>>(yh, stats, n2w, n2b, nullptr,
                                                (float*)d_out, nullptr, nullptr);
}

// Round 5
// 120.821 us; speedup vs baseline: 4.5775x; 1.5209x over previous
//
#include <hip/hip_runtime.h>
#include <hip/hip_bf16.h>

#define B_   8
#define S_   1024
#define D_   128
#define NH_  8
#define HD_  16
#define E_   4
#define HFF_ 512
#define NTOK (B_*S_)

typedef unsigned short ushort_t;
typedef __attribute__((ext_vector_type(8))) short bf16x8;
typedef __attribute__((ext_vector_type(4))) float f32x4;
typedef __attribute__((ext_vector_type(4))) _Float16 f16x4;

static __device__ __forceinline__ ushort_t f2bf(float f) {
    union { float f; unsigned u; } v; v.f = f;
    unsigned r = v.u + 0x7FFF + ((v.u >> 16) & 1);   // RNE
    return (ushort_t)(r >> 16);
}

// ---------------------------------------------------------------------------
// prep: x -> bf16; weights -> bf16 transposed layouts.
//   Wqkv_t [384][128], Wo_t [128][128],
//   W1t [4][512 cols][128 K]   (B^T per expert)
//   W2t [4][128 d][512 k2]     (B^T per expert)
// grid (1024, 5)
// ---------------------------------------------------------------------------
__global__ __launch_bounds__(256)
void prep(const float* __restrict__ x, const float* __restrict__ Wqkv,
          const float* __restrict__ Wo, const float* __restrict__ W1,
          const float* __restrict__ W2,
          ushort_t* __restrict__ xb, ushort_t* __restrict__ Wqkv_t,
          ushort_t* __restrict__ Wo_t, ushort_t* __restrict__ W1t,
          ushort_t* __restrict__ W2t)
{
    const int seg = blockIdx.y;
    const int i = blockIdx.x * 256 + threadIdx.x;
    if (seg == 0) {                       // x: 1048576 elems, 4/thread
        float4 v = ((const float4*)x)[i];
        ushort4 u; u.x = f2bf(v.x); u.y = f2bf(v.y); u.z = f2bf(v.z); u.w = f2bf(v.w);
        ((ushort4*)xb)[i] = u;
    } else if (seg == 1) {                // Wqkv [128][384] -> [384][128]
        if (i < D_ * 3 * D_) {
            int r = i / (3 * D_), c = i % (3 * D_);
            Wqkv_t[c * D_ + r] = f2bf(Wqkv[i]);
        }
    } else if (seg == 2) {                // Wo [128][128] -> T
        if (i < D_ * D_) {
            int r = i >> 7, c = i & 127;
            Wo_t[c * D_ + r] = f2bf(Wo[i]);
        }
    } else if (seg == 3) {                // W1 [4][128][512] -> [4][512][128]
        int e = i >> 16, rem = i & 65535, r = rem >> 9, c = rem & 511;
        W1t[e * 65536 + c * 128 + r] = f2bf(W1[i]);
    } else {                              // W2 [4][512][128] -> [4][128][512]
        int e = i >> 16, rem = i & 65535, k2 = rem >> 7, dd = rem & 127;
        W2t[e * 65536 + dd * 512 + k2] = f2bf(W2[i]);
    }
}

// ---------------------------------------------------------------------------
// 128x128-tile bf16 MFMA GEMM, 256 threads = 4 waves (2x2), 4x4 frags/wave.
// MODE 0: QKV: pack fp16 Q/K (scaled Q) [bh][s][16] and V^T [bh][d][s]
// MODE 1: f32 out = acc + bias[col] + extra[row*N+col]          (out-proj)
// ---------------------------------------------------------------------------
template<int MODE>
__global__ __launch_bounds__(256)
void gemm128(const ushort_t* __restrict__ A, const ushort_t* __restrict__ Bt,
             const float* __restrict__ bias, const float* __restrict__ extra,
             void* __restrict__ Cout, int M, int N, int K,
             _Float16* __restrict__ pq, _Float16* __restrict__ pk,
             _Float16* __restrict__ pv)
{
    __shared__ __align__(16) ushort_t As[4][128][8];   // [kchunk][m][8k]
    __shared__ __align__(16) ushort_t Bs[4][128][8];   // [kchunk][n][8k]
    const int bm = blockIdx.x * 128;
    const int bn = blockIdx.y * 128;
    const int tid = threadIdx.x;
    const int l = tid & 63, wv = tid >> 6;
    const int lc = l & 15, lg = l >> 4;
    const int wr = wv >> 1, wc = wv & 1;

    f32x4 acc[4][4] = {};

    const int srow = tid & 127, sch = tid >> 7;
    const ushort_t* ap = A + (size_t)(bm + srow) * K + sch * 8;
    const ushort_t* bp = Bt + (size_t)(bn + srow) * K + sch * 8;

    for (int k0 = 0; k0 < K; k0 += 32) {
        *(bf16x8*)As[sch][srow]     = *(const bf16x8*)(ap + k0);
        *(bf16x8*)As[sch + 2][srow] = *(const bf16x8*)(ap + k0 + 16);
        *(bf16x8*)Bs[sch][srow]     = *(const bf16x8*)(bp + k0);
        *(bf16x8*)Bs[sch + 2][srow] = *(const bf16x8*)(bp + k0 + 16);
        __syncthreads();
        bf16x8 af[4], bfr[4];
        #pragma unroll
        for (int f = 0; f < 4; f++) {
            af[f]  = *(const bf16x8*)As[lg][wr * 64 + f * 16 + lc];
            bfr[f] = *(const bf16x8*)Bs[lg][wc * 64 + f * 16 + lc];
        }
        #pragma unroll
        for (int fm = 0; fm < 4; fm++)
            #pragma unroll
            for (int fn = 0; fn < 4; fn++)
                acc[fm][fn] = __builtin_amdgcn_mfma_f32_16x16x32_bf16(
                    af[fm], bfr[fn], acc[fm][fn], 0, 0, 0);
        __syncthreads();
    }

    #pragma unroll
    for (int fm = 0; fm < 4; fm++) {
        #pragma unroll
        for (int rr = 0; rr < 4; rr++) {
            const int row = bm + wr * 64 + fm * 16 + lg * 4 + rr;
            #pragma unroll
            for (int fn = 0; fn < 4; fn++) {
                const int col = bn + wc * 64 + fn * 16 + lc;
                float v = acc[fm][fn][rr];
                if (MODE == 0) {
                    v += bias[col];
                    const int b = row >> 10, s = row & 1023;
                    const int part = col >> 7, hh = (col >> 4) & 7, dd = col & 15;
                    const size_t bh = (size_t)(b * NH_ + hh);
                    if (part == 0)
                        pq[(bh * 1024 + s) * HD_ + dd] = (_Float16)(v * 0.36067376022224085f);
                    else if (part == 1)
                        pk[(bh * 1024 + s) * HD_ + dd] = (_Float16)v;
                    else
                        pv[(bh << 14) + (dd << 10) + s] = (_Float16)v;
                } else {
                    const size_t off = (size_t)row * N + col;
                    ((float*)Cout)[off] = v + bias[col] + extra[off];
                }
            }
        }
    }
}

// ---------------------------------------------------------------------------
// Fused MoE FFN: per block 64 tokens x 1 expert.  grid (128, 4), 256 thr.
// GEMM1 chunk (64x128, K=128) -> relu+b1 -> bf16 LDS -> GEMM2 accum (K=128).
// ypart[e][tok][d] = g[tok,e] * (acc2 + b2[e,d]).  hid never hits HBM.
// LDS: As 16KB + WS 8KB + HS 16KB = 40KB.
// ---------------------------------------------------------------------------
__global__ __launch_bounds__(256)
void moe_fused(const ushort_t* __restrict__ hb, const ushort_t* __restrict__ W1t,
               const ushort_t* __restrict__ W2t, const float* __restrict__ b1,
               const float* __restrict__ b2, const float* __restrict__ gates,
               float* __restrict__ ypart)
{
    __shared__ __align__(16) ushort_t As[16][64][8];   // token tile [kchunk][tok][8]
    __shared__ __align__(16) ushort_t WS[4][128][8];   // weight k-step tile
    __shared__ __align__(16) ushort_t HS[16][64][8];   // hid chunk, GEMM2-A layout
    const int tb = blockIdx.x, e = blockIdx.y;
    const int tok0 = tb * 64;
    const int tid = threadIdx.x;
    const int l = tid & 63, wv = tid >> 6;
    const int lc = l & 15, lg = l >> 4;

    // stage token tile 64x128 once
    {
        const int row = tid & 63, part = tid >> 6;
        const ushort_t* src = hb + (size_t)(tok0 + row) * D_ + part * 32;
        #pragma unroll
        for (int j = 0; j < 4; j++)
            *(bf16x8*)As[part * 4 + j][row] = *(const bf16x8*)(src + j * 8);
    }

    const ushort_t* W1e = W1t + (size_t)e * HFF_ * D_;
    const ushort_t* W2e = W2t + (size_t)e * D_ * HFF_;
    const int wn = tid & 127, wj = tid >> 7;           // WS staging coords

    f32x4 acc2[4][2] = {};

    for (int c = 0; c < 4; c++) {
        f32x4 acc1[4][2] = {};
        #pragma unroll
        for (int ks = 0; ks < 4; ks++) {
            __syncthreads();                           // WS free (+As ready, 1st iter)
            const ushort_t* src = W1e + (size_t)(c * 128 + wn) * D_ + ks * 32 + wj * 16;
            *(bf16x8*)WS[wj * 2 + 0][wn] = *(const bf16x8*)src;
            *(bf16x8*)WS[wj * 2 + 1][wn] = *(const bf16x8*)(src + 8);
            __syncthreads();
            bf16x8 af[4], bf[2];
            #pragma unroll
            for (int f = 0; f < 4; f++) af[f] = *(const bf16x8*)As[ks * 4 + lg][f * 16 + lc];
            #pragma unroll
            for (int f = 0; f < 2; f++) bf[f] = *(const bf16x8*)WS[lg][wv * 32 + f * 16 + lc];
            #pragma unroll
            for (int fm = 0; fm < 4; fm++)
                #pragma unroll
                for (int fn = 0; fn < 2; fn++)
                    acc1[fm][fn] = __builtin_amdgcn_mfma_f32_16x16x32_bf16(
                        af[fm], bf[fn], acc1[fm][fn], 0, 0, 0);
        }
        // hid chunk -> HS (relu + b1), GEMM2 A-frag layout
        #pragma unroll
        for (int fm = 0; fm < 4; fm++)
            #pragma unroll
            for (int fn = 0; fn < 2; fn++)
                #pragma unroll
                for (int rr = 0; rr < 4; rr++) {
                    const int row = fm * 16 + lg * 4 + rr;
                    const int col = wv * 32 + fn * 16 + lc;
                    float v = fmaxf(acc1[fm][fn][rr] + b1[e * HFF_ + c * 128 + col], 0.f);
                    HS[col >> 3][row][col & 7] = f2bf(v);
                }
        __syncthreads();                               // HS visible
        #pragma unroll
        for (int ks2 = 0; ks2 < 4; ks2++) {
            if (ks2) __syncthreads();                  // WS free
            const ushort_t* src = W2e + (size_t)wn * HFF_ + c * 128 + ks2 * 32 + wj * 16;
            *(bf16x8*)WS[wj * 2 + 0][wn] = *(const bf16x8*)src;
            *(bf16x8*)WS[wj * 2 + 1][wn] = *(const bf16x8*)(src + 8);
            __syncthreads();
            bf16x8 af[4], bf[2];
            #pragma unroll
            for (int f = 0; f < 4; f++) af[f] = *(const bf16x8*)HS[ks2 * 4 + lg][f * 16 + lc];
            #pragma unroll
            for (int f = 0; f < 2; f++) bf[f] = *(const bf16x8*)WS[lg][wv * 32 + f * 16 + lc];
            #pragma unroll
            for (int fm = 0; fm < 4; fm++)
                #pragma unroll
                for (int fn = 0; fn < 2; fn++)
                    acc2[fm][fn] = __builtin_amdgcn_mfma_f32_16x16x32_bf16(
                        af[fm], bf[fn], acc2[fm][fn], 0, 0, 0);
        }
    }

    #pragma unroll
    for (int fm = 0; fm < 4; fm++)
        #pragma unroll
        for (int rr = 0; rr < 4; rr++) {
            const int row = fm * 16 + lg * 4 + rr;
            const float g = gates[(size_t)(tok0 + row) * E_ + e];
            #pragma unroll
            for (int fn = 0; fn < 2; fn++) {
                const int d = wv * 32 + fn * 16 + lc;
                ypart[((size_t)e * NTOK + tok0 + row) * D_ + d] =
                    g * (acc2[fm][fn][rr] + b2[e * D_ + d]);
            }
        }
}

// ---------------------------------------------------------------------------
// MFMA flash attention, no LDS. grid (B*NH, 8), block 256 (4 waves).
// ---------------------------------------------------------------------------
__global__ __launch_bounds__(256)
void attn_mfma(const _Float16* __restrict__ Qb, const _Float16* __restrict__ Kb,
               const _Float16* __restrict__ Vt, ushort_t* __restrict__ attno)
{
    const int bh = blockIdx.x;
    const int wv = threadIdx.x >> 6;
    const int l  = threadIdx.x & 63;
    const int r = l & 15, g = l >> 4;
    const int q0 = blockIdx.y * 128 + wv * 32;

    const _Float16* qp = Qb + ((size_t)bh << 14);
    const _Float16* kp = Kb + ((size_t)bh << 14);
    const _Float16* vp = Vt + ((size_t)bh << 14);

    f16x4 qf0 = *(const f16x4*)&qp[(q0 + r) * HD_ + g * 4];
    f16x4 qf1 = *(const f16x4*)&qp[(q0 + 16 + r) * HD_ + g * 4];

    f32x4 o0 = {}, o1 = {};
    float m0 = -1e30f, m1 = -1e30f, l0 = 0.f, l1 = 0.f;

    for (int it = 0; it < 32; ++it) {
        const int j0 = it * 32;
        f16x4 kf0 = *(const f16x4*)&kp[(j0 + r) * HD_ + g * 4];
        f16x4 kf1 = *(const f16x4*)&kp[(j0 + 16 + r) * HD_ + g * 4];
        f16x4 vf0 = *(const f16x4*)&vp[r * 1024 + j0 + g * 4];
        f16x4 vf1 = *(const f16x4*)&vp[r * 1024 + j0 + 16 + g * 4];

        f32x4 z = {};
        f32x4 s00 = __builtin_amdgcn_mfma_f32_16x16x16f16(kf0, qf0, z, 0, 0, 0);
        f32x4 s01 = __builtin_amdgcn_mfma_f32_16x16x16f16(kf1, qf0, z, 0, 0, 0);
        f32x4 s10 = __builtin_amdgcn_mfma_f32_16x16x16f16(kf0, qf1, z, 0, 0, 0);
        f32x4 s11 = __builtin_amdgcn_mfma_f32_16x16x16f16(kf1, qf1, z, 0, 0, 0);

        {
            float tm = fmaxf(fmaxf(fmaxf(s00[0], s00[1]), fmaxf(s00[2], s00[3])),
                             fmaxf(fmaxf(s01[0], s01[1]), fmaxf(s01[2], s01[3])));
            tm = fmaxf(tm, __shfl_xor(tm, 16));
            tm = fmaxf(tm, __shfl_xor(tm, 32));
            float mn = fmaxf(m0, tm);
            float al = exp2f(m0 - mn);
            m0 = mn;
            float p0 = exp2f(s00[0] - mn), p1 = exp2f(s00[1] - mn);
            float p2 = exp2f(s00[2] - mn), p3 = exp2f(s00[3] - mn);
            float p4 = exp2f(s01[0] - mn), p5 = exp2f(s01[1] - mn);
            float p6 = exp2f(s01[2] - mn), p7 = exp2f(s01[3] - mn);
            float ts = ((p0 + p1) + (p2 + p3)) + ((p4 + p5) + (p6 + p7));
            ts += __shfl_xor(ts, 16);
            ts += __shfl_xor(ts, 32);
            l0 = l0 * al + ts;
            o0 *= al;
            f16x4 pf0, pf1;
            pf0[0] = (_Float16)p0; pf0[1] = (_Float16)p1;
            pf0[2] = (_Float16)p2; pf0[3] = (_Float16)p3;
            pf1[0] = (_Float16)p4; pf1[1] = (_Float16)p5;
            pf1[2] = (_Float16)p6; pf1[3] = (_Float16)p7;
            o0 = __builtin_amdgcn_mfma_f32_16x16x16f16(vf0, pf0, o0, 0, 0, 0);
            o0 = __builtin_amdgcn_mfma_f32_16x16x16f16(vf1, pf1, o0, 0, 0, 0);
        }
        {
            float tm = fmaxf(fmaxf(fmaxf(s10[0], s10[1]), fmaxf(s10[2], s10[3])),
                             fmaxf(fmaxf(s11[0], s11[1]), fmaxf(s11[2], s11[3])));
            tm = fmaxf(tm, __shfl_xor(tm, 16));
            tm = fmaxf(tm, __shfl_xor(tm, 32));
            float mn = fmaxf(m1, tm);
            float al = exp2f(m1 - mn);
            m1 = mn;
            float p0 = exp2f(s10[0] - mn), p1 = exp2f(s10[1] - mn);
            float p2 = exp2f(s10[2] - mn), p3 = exp2f(s10[3] - mn);
            float p4 = exp2f(s11[0] - mn), p5 = exp2f(s11[1] - mn);
            float p6 = exp2f(s11[2] - mn), p7 = exp2f(s11[3] - mn);
            float ts = ((p0 + p1) + (p2 + p3)) + ((p4 + p5) + (p6 + p7));
            ts += __shfl_xor(ts, 16);
            ts += __shfl_xor(ts, 32);
            l1 = l1 * al + ts;
            o1 *= al;
            f16x4 pf0, pf1;
            pf0[0] = (_Float16)p0; pf0[1] = (_Float16)p1;
            pf0[2] = (_Float16)p2; pf0[3] = (_Float16)p3;
            pf1[0] = (_Float16)p4; pf1[1] = (_Float16)p5;
            pf1[2] = (_Float16)p6; pf1[3] = (_Float16)p7;
            o1 = __builtin_amdgcn_mfma_f32_16x16x16f16(vf0, pf0, o1, 0, 0, 0);
            o1 = __builtin_amdgcn_mfma_f32_16x16x16f16(vf1, pf1, o1, 0, 0, 0);
        }
    }

    const int b = bh >> 3, h = bh & 7;
    float inv0 = 1.f / l0, inv1 = 1.f / l1;
    ushort_t* op0 = attno + ((size_t)(b * S_ + q0 + r)) * D_ + h * HD_ + g * 4;
    ushort_t* op1 = attno + ((size_t)(b * S_ + q0 + 16 + r)) * D_ + h * HD_ + g * 4;
    #pragma unroll
    for (int i = 0; i < 4; i++) {
        op0[i] = f2bf(o0[i] * inv0);
        op1[i] = f2bf(o1[i] * inv1);
    }
}

// ---------------------------------------------------------------------------
// InstanceNorm stats (per (b,d) channel over S). grid (B, 32), 128 thr.
// ---------------------------------------------------------------------------
__global__ __launch_bounds__(128)
void in_stats_partial(const float* __restrict__ a, float* __restrict__ part)
{
    const int bb = blockIdx.x, chunk = blockIdx.y, d = threadIdx.x;
    const size_t base = (size_t)bb * S_ * D_ + (size_t)chunk * (S_ / 32) * D_ + d;
    float sum = 0.f, sq = 0.f;
    #pragma unroll 8
    for (int s = 0; s < S_ / 32; s++) {
        float v = a[base + (size_t)s * D_];
        sum += v; sq += v * v;
    }
    ((float2*)part)[(bb * 32 + chunk) * D_ + d] = make_float2(sum, sq);
}

// Fused: yh = h + sum_e ypart[e]; also emit per-chunk stats partials.
__global__ __launch_bounds__(128)
void moe_reduce_stats(const float* __restrict__ ypart, const float* __restrict__ h,
                      float* __restrict__ yh, float* __restrict__ part)
{
    const int bb = blockIdx.x, chunk = blockIdx.y, d = threadIdx.x;
    float sum = 0.f, sq = 0.f;
    for (int s = 0; s < 32; s++) {
        const size_t off = ((size_t)bb * 1024 + chunk * 32 + s) * D_ + d;
        float v = h[off] + ypart[off]
                + ypart[(size_t)1 * NTOK * D_ + off]
                + ypart[(size_t)2 * NTOK * D_ + off]
                + ypart[(size_t)3 * NTOK * D_ + off];
        yh[off] = v;
        sum += v; sq += v * v;
    }
    ((float2*)part)[(bb * 32 + chunk) * D_ + d] = make_float2(sum, sq);
}

__global__ __launch_bounds__(256)
void in_stats_combine(const float* __restrict__ part, float* __restrict__ stats)
{
    int bd = blockIdx.x * 256 + threadIdx.x;
    if (bd >= B_ * D_) return;
    int bb = bd >> 7, d = bd & 127;
    float sum = 0.f, sq = 0.f;
    const float2* pp = (const float2*)part;
    for (int c = 0; c < 32; c++) {
        float2 v = pp[(bb * 32 + c) * D_ + d];
        sum += v.x; sq += v.y;
    }
    const float invS = 1.f / (float)S_;
    float mu = sum * invS;
    float var = sq * invS - mu * mu;
    ((float2*)stats)[bd] = make_float2(mu, rsqrtf(var + 1e-5f));
}

// Apply norm; DUAL=1 additionally writes bf16 copy AND computes MoE gates.
template<int DUAL>
__global__ __launch_bounds__(256)
void in_apply(const float* __restrict__ a, const float* __restrict__ stats,
              const float* __restrict__ w, const float* __restrict__ bias,
              const float* __restrict__ wg, float* __restrict__ outp,
              ushort_t* __restrict__ outb, float* __restrict__ gates)
{
    size_t i4 = (size_t)blockIdx.x * 256 + threadIdx.x;
    int dq = (int)(i4 & 31);
    int tok = (int)(i4 >> 5);
    int bidx = tok >> 10;
    int d0 = dq * 4;
    float4 v = ((const float4*)a)[i4];
    const float2* st = (const float2*)stats;
    float2 s0 = st[bidx * D_ + d0 + 0];
    float2 s1 = st[bidx * D_ + d0 + 1];
    float2 s2 = st[bidx * D_ + d0 + 2];
    float2 s3 = st[bidx * D_ + d0 + 3];
    float4 r;
    r.x = (v.x - s0.x) * s0.y * w[d0 + 0] + bias[d0 + 0];
    r.y = (v.y - s1.x) * s1.y * w[d0 + 1] + bias[d0 + 1];
    r.z = (v.z - s2.x) * s2.y * w[d0 + 2] + bias[d0 + 2];
    r.w = (v.w - s3.x) * s3.y * w[d0 + 3] + bias[d0 + 3];
    ((float4*)outp)[i4] = r;
    if (DUAL) {
        ushort4 ub; ub.x = f2bf(r.x); ub.y = f2bf(r.y); ub.z = f2bf(r.z); ub.w = f2bf(r.w);
        ((ushort4*)outb)[i4] = ub;
        float rv[4] = {r.x, r.y, r.z, r.w};
        float4 aa = make_float4(0.f, 0.f, 0.f, 0.f);
        #pragma unroll
        for (int j = 0; j < 4; j++) {
            float4 wj = ((const float4*)wg)[d0 + j];
            aa.x += rv[j] * wj.x; aa.y += rv[j] * wj.y;
            aa.z += rv[j] * wj.z; aa.w += rv[j] * wj.w;
        }
        #pragma unroll
        for (int msk = 1; msk <= 16; msk <<= 1) {
            aa.x += __shfl_xor(aa.x, msk);
            aa.y += __shfl_xor(aa.y, msk);
            aa.z += __shfl_xor(aa.z, msk);
            aa.w += __shfl_xor(aa.w, msk);
        }
        if (dq == 0) {
            float lv[4] = {aa.x, aa.y, aa.z, aa.w};
            int i0 = 0; float mm0 = lv[0];
            #pragma unroll
            for (int k = 1; k < 4; k++) if (lv[k] > mm0) { mm0 = lv[k]; i0 = k; }
            int i1 = -1; float mm1 = -1e30f;
            #pragma unroll
            for (int k = 0; k < 4; k++) {
                if (k == i0) continue;
                if (lv[k] > mm1) { mm1 = lv[k]; i1 = k; }
            }
            float te = __expf(mm1 - mm0);
            float g0 = 1.f / (1.f + te);
            float g1 = te * g0;
            float gg[4] = {0.f, 0.f, 0.f, 0.f};
            gg[i0] = g0; gg[i1] = g1;
            *(float4*)&gates[(size_t)tok * E_] = make_float4(gg[0], gg[1], gg[2], gg[3]);
        }
    }
}

// ---------------------------------------------------------------------------
// Launch
// ---------------------------------------------------------------------------
extern "C" void kernel_launch(void* const* d_in, const int* in_sizes, int n_in,
                              void* d_out, int out_size, void* d_ws, size_t ws_size,
                              hipStream_t stream)
{
    const float* x    = (const float*)d_in[0];
    const float* Wqkv = (const float*)d_in[1];
    const float* bqkv = (const float*)d_in[2];
    const float* Wo   = (const float*)d_in[3];
    const float* bo   = (const float*)d_in[4];
    const float* n1w  = (const float*)d_in[5];
    const float* n1b  = (const float*)d_in[6];
    const float* n2w  = (const float*)d_in[7];
    const float* n2b  = (const float*)d_in[8];
    const float* wg   = (const float*)d_in[9];
    const float* W1   = (const float*)d_in[10];
    const float* b1   = (const float*)d_in[11];
    const float* W2   = (const float*)d_in[12];
    const float* b2   = (const float*)d_in[13];

    // Workspace layout (~41.6 MB)
    char* ws = (char*)d_ws;
    _Float16* Qb     = (_Float16*)(ws);                          // [0,2M)
    _Float16* Kb     = (_Float16*)(ws + (2u << 20));             // [2,4M)
    _Float16* Vt     = (_Float16*)(ws + (4u << 20));             // [4,6M)
    ushort_t* attno  = (ushort_t*)(ws + (6u << 20));             // [6,8M)
    float*    t      = (float*)(ws + (8u << 20));                // [8,12M)
    float*    h      = (float*)(ws + (12u << 20));               // [12,16M)
    ushort_t* hb     = (ushort_t*)(ws + (16u << 20));            // [16,18M)
    float*    ypart  = (float*)(ws + (18u << 20));               // [18,34M)
    float*    yh     = (float*)(ws + (34u << 20));               // [34,38M)
    ushort_t* xb     = (ushort_t*)(ws + (38u << 20));            // [38,40M)
    char*     wbase  = ws + (40u << 20);
    ushort_t* Wqkv_t = (ushort_t*)(wbase);                       // 96 KB
    ushort_t* Wo_t   = (ushort_t*)(wbase + (128u << 10));        // 32 KB
    ushort_t* W1t    = (ushort_t*)(wbase + (192u << 10));        // 512 KB
    ushort_t* W2t    = (ushort_t*)(wbase + (704u << 10));        // 512 KB
    float*    gates  = (float*)(wbase + (1216u << 10));          // 128 KB
    float*    pstat  = (float*)(wbase + (1344u << 10));          // 256 KB
    float*    stats  = (float*)(wbase + (1600u << 10));          // 8 KB

    dim3 blk(256);

    // 0. bf16 conversions + weight transposes
    prep<<<dim3(1024, 5), blk, 0, stream>>>(x, Wqkv, Wo, W1, W2,
                                            xb, Wqkv_t, Wo_t, W1t, W2t);
    // 1. QKV projection with fused fp16 Q/K/V^T pack
    gemm128<0><<<dim3(64, 3), blk, 0, stream>>>(
        xb, Wqkv_t, bqkv, nullptr, nullptr, NTOK, 3 * D_, D_, Qb, Kb, Vt);
    // 2. MFMA flash attention -> attno (bf16)
    attn_mfma<<<dim3(64, 8), blk, 0, stream>>>(Qb, Kb, Vt, attno);
    // 3. out-proj + bias + residual(x) -> t (f32)
    gemm128<1><<<dim3(64, 1), blk, 0, stream>>>(
        attno, Wo_t, bo, x, t, NTOK, D_, D_, nullptr, nullptr, nullptr);
    // 4. InstanceNorm 1 -> h (f32) + hb (bf16) + fused gating
    in_stats_partial<<<dim3(B_, 32), dim3(128), 0, stream>>>(t, pstat);
    in_stats_combine<<<dim3(4), blk, 0, stream>>>(pstat, stats);
    in_apply<1><<<dim3(1024), blk, 0, stream>>>(t, stats, n1w, n1b, wg, h, hb, gates);
    // 5. Fused MoE FFN -> ypart[4][NTOK][D]
    moe_fused<<<dim3(128, 4), blk, 0, stream>>>(hb, W1t, W2t, b1, b2, gates, ypart);
    // 6. Reduce experts + residual(h) -> yh, fused norm2 partial stats
    moe_reduce_stats<<<dim3(B_, 32), dim3(128), 0, stream>>>(ypart, h, yh, pstat);
    in_stats_combine<<<dim3(4), blk, 0, stream>>>(pstat, stats);
    in_apply<0><<<dim3(1024), blk, 0, stream>>>(yh, stats, n2w, n2b, nullptr,
                                                (float*)d_out, nullptr, nullptr);
}